// Round 9
// baseline (1516.172 us; speedup 1.0000x reference)
//
#include <hip/hip_runtime.h>

#define BB 64
#define TT 60
#define LL 49
#define HID 768
#define E2 1536
#define K2 2304          // E2 + HID (concat for s_t GEMM)
#define VOC 10000
#define BT (BB*TT)      // 3840
#define BL (BB*LL)      // 3136
#define NPAD_MLP 10240
#define NPAD_S 128

typedef __bf16 bf16x8 __attribute__((ext_vector_type(8)));
typedef float f32x4 __attribute__((ext_vector_type(4)));

__device__ __forceinline__ unsigned short f2bf(float f) {
  union { float f; unsigned int u; } v; v.f = f;
  unsigned int u = v.u;
  return (unsigned short)((u + 0x7fffu + ((u >> 16) & 1u)) >> 16);  // RNE
}
__device__ __forceinline__ float bf2f(unsigned short h) {
  union { unsigned int u; float f; } v; v.u = ((unsigned int)h) << 16;
  return v.f;
}
__device__ __forceinline__ float fast_tanh(float x) {
  float e = __expf(2.f * x);
  return 1.f - 2.f / (e + 1.f);
}
__device__ __forceinline__ float fast_sigmoid(float x) {
  return 1.f / (1.f + __expf(-x));
}

// ---------------- fused convert with strided destination ----------------
#define NSEG 14
#define CHUNK4 2048
struct SegT {
  const float* src;
  unsigned short* dst;
  int n4;        // total vec4 elements (source-logical)
  int rl4;       // source row length in vec4
  int dstride4;  // dst row stride in vec4
  int dcol4;     // dst col offset in vec4
  int nrows;     // valid rows (mode 1)
  int mode;      // 0 plain, 1 pad-rows, 2 timestep-shift
  int blk0;
};
struct SegTable { SegT s[NSEG]; };

__global__ __launch_bounds__(256) void k_convall(SegTable tab) {
  int b = blockIdx.x;
  int si = 0;
#pragma unroll
  for (int i = 1; i < NSEG; ++i) si += (b >= tab.s[i].blk0);
  SegT sg = tab.s[si];
  int lb = b - sg.blk0;
  int end = (lb + 1) * CHUNK4; end = end < sg.n4 ? end : sg.n4;
  for (int i = lb * CHUNK4 + threadIdx.x; i < end; i += 256) {
    int row = i / sg.rl4, c = i - row * sg.rl4;
    ushort4 o; o.x = o.y = o.z = o.w = 0;
    if (sg.mode == 0) {
      float4 v = ((const float4*)sg.src)[i];
      o.x = f2bf(v.x); o.y = f2bf(v.y); o.z = f2bf(v.z); o.w = f2bf(v.w);
    } else if (sg.mode == 1) {
      if (row < sg.nrows) {
        float4 v = ((const float4*)sg.src)[i];
        o.x = f2bf(v.x); o.y = f2bf(v.y); o.z = f2bf(v.z); o.w = f2bf(v.w);
      }
    } else {  // timestep shift: row bt -> src row bt-1, zeros at t==0
      if (row % TT != 0) {
        float4 v = ((const float4*)sg.src)[i - sg.rl4];
        o.x = f2bf(v.x); o.y = f2bf(v.y); o.z = f2bf(v.z); o.w = f2bf(v.w);
      }
    }
    ((ushort4*)sg.dst)[(size_t)row * sg.dstride4 + sg.dcol4 + c] = o;
  }
}

// ---------------- k_xmean: xm[b,c] = bf16(mean_t x[b,t,c]) ----------------
__global__ __launch_bounds__(256) void k_xmean(const float* __restrict__ x,
                                               unsigned short* __restrict__ xm) {
  int b = blockIdx.x / 6;
  int c = (blockIdx.x % 6) * 256 + threadIdx.x;
  float s = 0.f;
  for (int t = 0; t < TT; ++t) s += x[((size_t)b * TT + t) * E2 + c];
  xm[(size_t)b * E2 + c] = f2bf(s * (1.f / 60.f));
}

// ---------------- segmented 128^2 2-phase GEMM (skinny N=64 GEMMs) ----------------
struct SSeg {
  const unsigned short* A; const unsigned short* B; float* C;
  int M, Nout, K, nMblk, blk0;
};
#define NSSEG 3
struct SSegTable { SSeg s[NSSEG]; };

__global__ __launch_bounds__(256) void gemm_bt_seg(SSegTable tab)
{
  __shared__ __attribute__((aligned(16))) unsigned short As[128*32];
  __shared__ __attribute__((aligned(16))) unsigned short Bs[128*32];
  const int tid  = threadIdx.x;
  const int lane = tid & 63;
  const int wave = tid >> 6;

  const int nwg = gridDim.x;
  const int id  = blockIdx.x;
  const int q = nwg >> 3, r = nwg & 7;
  const int xcd = id & 7, lo = id >> 3;
  const int wgid = (xcd < r ? xcd * (q + 1) : r * (q + 1) + (xcd - r) * q) + lo;

  int si = 0;
#pragma unroll
  for (int i = 1; i < NSSEG; ++i) si += (wgid >= tab.s[i].blk0);
  const SSeg sg = tab.s[si];
  const int lwg = wgid - sg.blk0;
  const int mb = lwg % sg.nMblk;
  const int nb = lwg / sg.nMblk;
  const int M = sg.M, Nout = sg.Nout, K = sg.K;
  const unsigned short* __restrict__ A  = sg.A;
  const unsigned short* __restrict__ Bw = sg.B;
  float* __restrict__ C = sg.C;
  const int m0 = mb * 128;
  const int n0 = nb * 128;
  const int wm = (wave >> 1) * 64;
  const int wn = (wave & 1) * 64;

  f32x4 acc[4][4];
#pragma unroll
  for (int i = 0; i < 4; ++i)
#pragma unroll
    for (int j = 0; j < 4; ++j) acc[i][j] = f32x4{0.f, 0.f, 0.f, 0.f};

  const int lrow = lane & 15;
  const int kb   = (lane >> 4) * 8;

  for (int k0 = 0; k0 < K; k0 += 32) {
    __syncthreads();
#pragma unroll
    for (int p = 0; p < 2; ++p) {
      int slot = p * 256 + wave * 64 + lane;
      int row = slot >> 2, c8 = slot & 3;
      int ar = m0 + row; ar = ar < M ? ar : (M - 1);
      const unsigned short* asrc = A + (size_t)ar * K + k0 + c8 * 8;
      __builtin_amdgcn_global_load_lds(
          (const __attribute__((address_space(1))) void*)asrc,
          (__attribute__((address_space(3))) void*)&As[(p * 256 + wave * 64) * 8],
          16, 0, 0);
      const unsigned short* bsrc = Bw + (size_t)(n0 + row) * K + k0 + c8 * 8;
      __builtin_amdgcn_global_load_lds(
          (const __attribute__((address_space(1))) void*)bsrc,
          (__attribute__((address_space(3))) void*)&Bs[(p * 256 + wave * 64) * 8],
          16, 0, 0);
    }
    __syncthreads();

    bf16x8 av[4], bv[4];
#pragma unroll
    for (int i = 0; i < 4; ++i)
      av[i] = *(const bf16x8*)&As[(wm + i * 16 + lrow) * 32 + kb];
#pragma unroll
    for (int j = 0; j < 4; ++j)
      bv[j] = *(const bf16x8*)&Bs[(wn + j * 16 + lrow) * 32 + kb];
#pragma unroll
    for (int i = 0; i < 4; ++i)
#pragma unroll
      for (int j = 0; j < 4; ++j)
        acc[i][j] = __builtin_amdgcn_mfma_f32_16x16x32_bf16(av[i], bv[j], acc[i][j], 0, 0, 0);
  }

  const int cr = (lane >> 4) * 4;
  const int cc = lane & 15;
#pragma unroll
  for (int i = 0; i < 4; ++i) {
    int row0 = m0 + wm + i * 16 + cr;
#pragma unroll
    for (int j = 0; j < 4; ++j) {
      int col = n0 + wn + j * 16 + cc;
      if (col < Nout) {
#pragma unroll
        for (int r2 = 0; r2 < 4; ++r2) {
          int row = row0 + r2;
          if (row < M) C[(size_t)row * Nout + col] = acc[i][j][r2];
        }
      }
    }
  }
}

// ---------------- 256^2 lean pipelined GEMM: BK=32, 2-buffer, 64KB -> 2 blk/CU ----------------
// R6's lean PH0/PH1 core (wave-tile 128x64, 43.7 FLOP/LDS-byte) with 2-buffer
// layout so the LDS request is 65536 B: 2 blocks/CU (130KB LDS, 4 waves/SIMD x
// 128 VGPR = full file). Tile kt uses buf c=kt&1. PH0(kt) stages B(kt+1)->buf
// c^1 (dead since barrier closing kt-1); PH1(kt) stages A(kt+2)->buf c (A(c)
// reads finished at PH0's closing barrier; PH1 carries A in registers). VM2 at
// tile end provably drains tile kt+1's A+B (counted vmcnt, never 0 mid-loop).
// Swizzle (both-sides, rule #21): 16B-slot s' = s ^ ((row>>1)&3).
// LDS buf: A 16KB @ +0, B 16KB @ +16384, stride 32768.
// Epilogue modes: 0 = fp32 C + optional bias; 1 = bf16 sigmoid(acc)*tanh(aux).
#define BARR() do { asm volatile("" ::: "memory"); __builtin_amdgcn_s_barrier(); \
                    asm volatile("" ::: "memory"); } while (0)
#define VM2() asm volatile("s_waitcnt vmcnt(2)" ::: "memory")
#define VM0() asm volatile("s_waitcnt vmcnt(0)" ::: "memory")

#define STAGE_OP(bufi, op, kt) do {                                             \
  int k0_ = (kt) * 32;                                                          \
  _Pragma("unroll")                                                             \
  for (int l_ = 0; l_ < 2; ++l_) {                                              \
    int rr_ = l_ * 128 + sr0;                                                   \
    int ss_ = ssp ^ ((rr_ >> 1) & 3);                                           \
    int gr_;                                                                    \
    if (op) gr_ = n0 + rr_;                                                     \
    else    gr_ = CLAMP ? ((m0 + rr_) < M ? (m0 + rr_) : (M - 1)) : (m0 + rr_); \
    const unsigned short* src_ = ((op) ? Bw : Ap) + (size_t)gr_ * K + k0_ + ss_ * 8; \
    char* dst_ = smem + (bufi) * 32768 + (op) * 16384 + l_ * 8192 + w * 1024;   \
    __builtin_amdgcn_global_load_lds(                                           \
        (const __attribute__((address_space(1))) void*)src_,                    \
        (__attribute__((address_space(3))) void*)dst_, 16, 0, 0);               \
  }                                                                             \
} while (0)

#define LDA(bufi, row) (*(const bf16x8*)(smem + (bufi) * 32768 + (row) * 64 + (cg ^ (((row) >> 1) & 3)) * 16))
#define LDB(bufi, row) (*(const bf16x8*)(smem + (bufi) * 32768 + 16384 + (row) * 64 + (cg ^ (((row) >> 1) & 3)) * 16))

#define PH0(bufi, STAGE_STMT) do {                                              \
  STAGE_STMT;                                                                   \
  bf16x8 bfr0 = LDB(bufi, wn + lrow);                                           \
  bf16x8 bfr1 = LDB(bufi, wn + 16 + lrow);                                      \
  _Pragma("unroll")                                                             \
  for (int i_ = 0; i_ < 8; ++i_) afr[i_] = LDA(bufi, wm + i_ * 16 + lrow);      \
  __builtin_amdgcn_s_setprio(1);                                                \
  _Pragma("unroll")                                                             \
  for (int i_ = 0; i_ < 8; ++i_) {                                              \
    acc[i_][0] = __builtin_amdgcn_mfma_f32_16x16x32_bf16(afr[i_], bfr0, acc[i_][0], 0, 0, 0); \
    acc[i_][1] = __builtin_amdgcn_mfma_f32_16x16x32_bf16(afr[i_], bfr1, acc[i_][1], 0, 0, 0); \
  }                                                                             \
  __builtin_amdgcn_s_setprio(0);                                                \
  BARR();                                                                       \
} while (0)

#define PH1(bufi, STAGE_STMT, VM_STMT) do {                                     \
  STAGE_STMT;                                                                   \
  bf16x8 bfr0 = LDB(bufi, wn + 32 + lrow);                                      \
  bf16x8 bfr1 = LDB(bufi, wn + 48 + lrow);                                      \
  __builtin_amdgcn_s_setprio(1);                                                \
  _Pragma("unroll")                                                             \
  for (int i_ = 0; i_ < 8; ++i_) {                                              \
    acc[i_][2] = __builtin_amdgcn_mfma_f32_16x16x32_bf16(afr[i_], bfr0, acc[i_][2], 0, 0, 0); \
    acc[i_][3] = __builtin_amdgcn_mfma_f32_16x16x32_bf16(afr[i_], bfr1, acc[i_][3], 0, 0, 0); \
  }                                                                             \
  __builtin_amdgcn_s_setprio(0);                                                \
  VM_STMT;                                                                      \
  BARR();                                                                       \
} while (0)

struct GSeg {
  const unsigned short* A; const unsigned short* B; float* C;
  const float* bias;
  const float* aux;           // cells (emode 1)
  unsigned short* outbf;      // bf16 output (emode 1)
  int M, Nout, K, nMblk, blk0, emode;
};
#define NGSEG 5
struct GSegTable { GSeg s[NGSEG]; };

template <bool CLAMP>
__global__ __launch_bounds__(512, 4) void gemm8p(GSegTable tab)
{
  extern __shared__ char smem[];
  const int tid  = threadIdx.x;
  const int lane = tid & 63;
  const int w    = tid >> 6;              // 0..7
  const int lrow = lane & 15;
  const int cg   = lane >> 4;             // logical 16B slot
  const int sr0  = w * 16 + (lane >> 2);  // stage row (l_=0)
  const int ssp  = lane & 3;              // physical 16B slot

  const int nwg = gridDim.x;
  const int id  = blockIdx.x;
  const int q = nwg >> 3, r = nwg & 7;
  const int xcd = id & 7, lo = id >> 3;
  const int wgid = (xcd < r ? xcd * (q + 1) : r * (q + 1) + (xcd - r) * q) + lo;

  int si = 0;
#pragma unroll
  for (int i = 1; i < NGSEG; ++i) si += (wgid >= tab.s[i].blk0);
  const GSeg sg = tab.s[si];
  const int lwg = wgid - sg.blk0;
  const int mb = lwg % sg.nMblk;
  const int nb = lwg / sg.nMblk;
  const int M = sg.M, Nout = sg.Nout, K = sg.K;
  const unsigned short* __restrict__ Ap = sg.A;
  const unsigned short* __restrict__ Bw = sg.B;

  const int m0 = mb * 256;
  const int n0 = nb * 256;
  const int wm = (w >> 2) * 128;   // 0 or 128
  const int wn = (w & 3) * 64;     // 0,64,128,192

  f32x4 acc[8][4];
#pragma unroll
  for (int i = 0; i < 8; ++i)
#pragma unroll
    for (int j = 0; j < 4; ++j) acc[i][j] = f32x4{0.f, 0.f, 0.f, 0.f};
  bf16x8 afr[8];

  const int NT = K >> 5;  // K/32, >= 3

  // prologue: A(0),B(0),A(1) = 6 loads; VM2 -> tile0's 4 arrived
  STAGE_OP(0, 0, 0);
  STAGE_OP(0, 1, 0);
  STAGE_OP(1, 0, 1);
  VM2();
  BARR();

  for (int kt = 0; kt < NT - 2; ++kt) {
    const int c = kt & 1;
    PH0(c, STAGE_OP(c ^ 1, 1, kt + 1));        // B(kt+1) -> dead buf
    PH1(c, STAGE_OP(c, 0, kt + 2), VM2(););    // A(kt+2) -> current buf (A reads done)
  }
  {
    const int c = (NT - 2) & 1;
    PH0(c, STAGE_OP(c ^ 1, 1, NT - 1));
    PH1(c, ;, VM0(););
  }
  {
    const int c = (NT - 1) & 1;
    PH0(c, ;);
    PH1(c, ;, ;);
  }

  // epilogue: C/D layout col=lane&15, row=(lane>>4)*4+reg
  if (sg.emode == 0) {
    float* __restrict__ C = sg.C;
    const float* __restrict__ bias = sg.bias;
#pragma unroll
    for (int i = 0; i < 8; ++i) {
      int row0 = m0 + wm + i * 16 + (lane >> 4) * 4;
#pragma unroll
      for (int j = 0; j < 4; ++j) {
        int col = n0 + wn + j * 16 + (lane & 15);
        if (col < Nout) {
          float badd = bias ? bias[col] : 0.f;
#pragma unroll
          for (int r2 = 0; r2 < 4; ++r2) {
            int row = row0 + r2;
            if (!CLAMP || row < M) C[(size_t)row * Nout + col] = acc[i][j][r2] + badd;
          }
        }
      }
    }
  } else {
    // s_t epilogue: bf16( sigmoid(acc) * tanh(cells) )
    const float* __restrict__ cells = sg.aux;
    unsigned short* __restrict__ ob = sg.outbf;
#pragma unroll
    for (int i = 0; i < 8; ++i) {
      int row0 = m0 + wm + i * 16 + (lane >> 4) * 4;
#pragma unroll
      for (int j = 0; j < 4; ++j) {
        int col = n0 + wn + j * 16 + (lane & 15);
        if (col < Nout) {
#pragma unroll
          for (int r2 = 0; r2 < 4; ++r2) {
            int row = row0 + r2;
            if (!CLAMP || row < M) {
              float cv = cells[(size_t)row * Nout + col];
              ob[(size_t)row * Nout + col] = f2bf(fast_sigmoid(acc[i][j][r2]) * fast_tanh(cv));
            }
          }
        }
      }
    }
  }
}

// ---------------- E3: switch softmax + V ----------------
__global__ __launch_bounds__(256) void k_switch(
    const float* __restrict__ AH, const float* __restrict__ AG,
    const float* __restrict__ q, const float* __restrict__ wsw,
    const float* __restrict__ H, const float* __restrict__ G,
    unsigned short* __restrict__ Vbf, float* __restrict__ sw_out)
{
  int bl = blockIdx.x;
  int b = bl / LL;
  int tid = threadIdx.x;
  float aH = 0.f, aG = 0.f;
  for (int h = tid; h < HID; h += 256) {
    float qv = q[b * HID + h], w = wsw[h];
    aH += fast_tanh(AH[(size_t)bl * HID + h] + qv) * w;
    aG += fast_tanh(AG[(size_t)bl * HID + h] + qv) * w;
  }
#pragma unroll
  for (int off = 32; off > 0; off >>= 1) {
    aH += __shfl_down(aH, off);
    aG += __shfl_down(aG, off);
  }
  __shared__ float redH[4], redG[4];
  int lane = tid & 63, wave = tid >> 6;
  if (lane == 0) { redH[wave] = aH; redG[wave] = aG; }
  __syncthreads();
  float sH = redH[0] + redH[1] + redH[2] + redH[3];
  float sG = redG[0] + redG[1] + redG[2] + redG[3];
  float m = fmaxf(sH, sG);
  float e0 = __expf(sH - m), e1 = __expf(sG - m);
  float inv = 1.f / (e0 + e1);
  float sw0 = e0 * inv, sw1 = e1 * inv;
  if (tid == 0) { sw_out[bl * 2] = sw0; sw_out[bl * 2 + 1] = sw1; }
  for (int h = tid; h < HID; h += 256) {
    float v = sw0 * H[(size_t)bl * HID + h] + sw1 * G[(size_t)bl * HID + h];
    Vbf[(size_t)bl * HID + h] = f2bf(v);
  }
}

// ---------------- E4: z_t/z_s -> alpha/beta -> c_hat+hiddens ----------------
__global__ __launch_bounds__(256) void k_attn(
    const float* __restrict__ PV, const float* __restrict__ PG,
    const float* __restrict__ SS, const float* __restrict__ wh,
    const unsigned short* __restrict__ stbf, const unsigned short* __restrict__ Vbf,
    const float* __restrict__ hiddens,
    float* __restrict__ alpha_out, float* __restrict__ beta_out,
    unsigned short* __restrict__ chh)
{
  const int TG = 4;
  int b  = blockIdx.x / (TT / TG);
  int t0 = (blockIdx.x % (TT / TG)) * TG;
  int tid = threadIdx.x;
  __shared__ float pg_s[TG][LL], wh_s[LL], zz[TG][LL + 1], alpha_s[TG][LL], beta_sh[TG];

  if (tid < LL) wh_s[tid] = wh[tid];
  if (tid < TG * LL) {
    int tt = tid / LL, k = tid - tt * LL;
    pg_s[tt][k] = PG[(size_t)(b * TT + t0 + tt) * 64 + k];
  }
  __syncthreads();

  if (tid < TG * (LL + 1)) {
    int tt = tid / (LL + 1), l = tid - tt * (LL + 1);
    const float* src = (l < LL) ? &PV[((size_t)b * LL + l) * 64]
                                : &SS[(size_t)(b * TT + t0 + tt) * 64];
    float acc = 0.f;
    for (int k = 0; k < LL; ++k) acc += fast_tanh(src[k] + pg_s[tt][k]) * wh_s[k];
    zz[tt][l] = acc;
  }
  __syncthreads();

  if (tid < TG) {
    int tt = tid, bt = b * TT + t0 + tt;
    float mx = -1e30f;
    for (int l = 0; l < LL; ++l) mx = fmaxf(mx, zz[tt][l]);
    float sum = 0.f;
    for (int l = 0; l < LL; ++l) { float e = __expf(zz[tt][l] - mx); alpha_s[tt][l] = e; sum += e; }
    float inv = 1.f / sum;
    for (int l = 0; l < LL; ++l) {
      alpha_s[tt][l] *= inv;
      alpha_out[(size_t)bt * LL + l] = alpha_s[tt][l];
    }
    float mx2 = fmaxf(mx, zz[tt][LL]);
    float s2 = 0.f;
    for (int l = 0; l <= LL; ++l) s2 += __expf(zz[tt][l] - mx2);
    float bet = __expf(zz[tt][LL] - mx2) / s2;
    beta_sh[tt] = bet;
    beta_out[bt] = bet;
  }
  __syncthreads();

  for (int h = tid; h < HID; h += 256) {
    float ct[TG] = {0.f, 0.f, 0.f, 0.f};
    for (int l = 0; l < LL; ++l) {
      float v = bf2f(Vbf[((size_t)b * LL + l) * HID + h]);
#pragma unroll
      for (int tt = 0; tt < TG; ++tt) ct[tt] += alpha_s[tt][l] * v;
    }
#pragma unroll
    for (int tt = 0; tt < TG; ++tt) {
      int bt = b * TT + t0 + tt;
      float bet = beta_sh[tt];
      float s = bf2f(stbf[(size_t)bt * HID + h]);
      float chat = bet * s + (1.f - bet) * ct[tt];
      chh[(size_t)bt * HID + h] = f2bf(chat + hiddens[(size_t)bt * HID + h]);
    }
  }
}

// ---------------- launcher ----------------
extern "C" void kernel_launch(void* const* d_in, const int* in_sizes, int n_in,
                              void* d_out, int out_size, void* d_ws, size_t ws_size,
                              hipStream_t stream)
{
  const float* x       = (const float*)d_in[0];
  const float* hiddens = (const float*)d_in[1];
  const float* cells   = (const float*)d_in[2];
  const float* G       = (const float*)d_in[3];
  const float* H       = (const float*)d_in[4];
  const float* W_sx    = (const float*)d_in[5];
  const float* W_sh    = (const float*)d_in[6];
  const float* W_ax    = (const float*)d_in[7];
  const float* W_ah    = (const float*)d_in[8];
  const float* W_ag    = (const float*)d_in[9];
  const float* w_sw    = (const float*)d_in[10];
  const float* Wv      = (const float*)d_in[11];
  const float* Wg      = (const float*)d_in[12];
  const float* Ws      = (const float*)d_in[13];
  const float* wh      = (const float*)d_in[14];
  const float* W_mlp   = (const float*)d_in[15];
  const float* b_mlp   = (const float*)d_in[16];

  float* scores = (float*)d_out;
  float* alpha  = scores + (size_t)BT * VOC;
  float* beta   = alpha + (size_t)BT * LL;
  float* swout  = beta + BT;

  char* wsp = (char*)d_ws;
  size_t off = 0;
  auto alloc = [&](size_t bytes) -> char* {
    char* p = wsp + off;
    off += (bytes + 255) & ~(size_t)255;
    return p;
  };

  unsigned short* xh     = (unsigned short*)alloc((size_t)BT * K2 * 2);   // [x | hprev]
  unsigned short* wsxh   = (unsigned short*)alloc((size_t)HID * K2 * 2);  // [W_sx | W_sh]
  unsigned short* waxb   = (unsigned short*)alloc((size_t)HID * E2 * 2);
  unsigned short* wahb   = (unsigned short*)alloc((size_t)HID * HID * 2);
  unsigned short* wagb   = (unsigned short*)alloc((size_t)HID * HID * 2);
  unsigned short* Hbf    = (unsigned short*)alloc((size_t)BL * HID * 2);
  unsigned short* Gbf    = (unsigned short*)alloc((size_t)BL * HID * 2);
  unsigned short* hidbf  = (unsigned short*)alloc((size_t)BT * HID * 2);
  unsigned short* wvb    = (unsigned short*)alloc((size_t)NPAD_S * HID * 2);
  unsigned short* wgb    = (unsigned short*)alloc((size_t)NPAD_S * HID * 2);
  unsigned short* wsb    = (unsigned short*)alloc((size_t)NPAD_S * HID * 2);
  unsigned short* wmlpb  = (unsigned short*)alloc((size_t)NPAD_MLP * HID * 2);
  unsigned short* Vbf    = (unsigned short*)alloc((size_t)BL * HID * 2);
  unsigned short* stbf   = (unsigned short*)alloc((size_t)BT * HID * 2);
  unsigned short* chh    = (unsigned short*)alloc((size_t)BT * HID * 2);
  unsigned short* xmbf   = (unsigned short*)alloc((size_t)BB * E2 * 2);
  float* AH = (float*)alloc((size_t)BL * HID * 4);
  float* AG = (float*)alloc((size_t)BL * HID * 4);
  float* qb = (float*)alloc((size_t)BB * HID * 4);
  float* PV = (float*)alloc((size_t)BL * 64 * 4);
  float* PG = (float*)alloc((size_t)BT * 64 * 4);
  float* SS = (float*)alloc((size_t)BT * 64 * 4);
  (void)ws_size; (void)in_sizes; (void)n_in; (void)out_size;

  // --- 1: fused converts (strided-dst) ---
  SegTable tab;
  int blk = 0, si = 0;
  auto seg = [&](const float* s, unsigned short* d, int n4, int rl4, int dstride4,
                 int dcol4, int nrows, int mode) {
    tab.s[si].src = s; tab.s[si].dst = d; tab.s[si].n4 = n4; tab.s[si].rl4 = rl4;
    tab.s[si].dstride4 = dstride4; tab.s[si].dcol4 = dcol4;
    tab.s[si].nrows = nrows; tab.s[si].mode = mode; tab.s[si].blk0 = blk;
    blk += (n4 + CHUNK4 - 1) / CHUNK4; ++si;
  };
  seg(W_sx,    wsxh,  HID * 384, 384, 576, 0,   0, 0);
  seg(W_sh,    wsxh,  HID * 192, 192, 576, 384, 0, 0);
  seg(x,       xh,    BT * 384,  384, 576, 0,   0, 0);
  seg(hiddens, xh,    BT * 192,  192, 576, 384, 0, 2);   // shifted h_{t-1}
  seg(W_ax,    waxb,  HID * 384, 384, 384, 0,   0, 0);
  seg(W_ah,    wahb,  HID * 192, 192, 192, 0,   0, 0);
  seg(W_ag,    wagb,  HID * 192, 192, 192, 0,   0, 0);
  seg(H,       Hbf,   BL * 192,  192, 192, 0,   0, 0);
  seg(G,       Gbf,   BL * 192,  192, 192, 0,   0, 0);
  seg(hiddens, hidbf, BT * 192,  192, 192, 0,   0, 0);
  seg(Wv,      wvb,   NPAD_S * 192, 192, 192, 0, LL, 1);
  seg(Wg,      wgb,   NPAD_S * 192, 192, 192, 0, LL, 1);
  seg(Ws,      wsb,   NPAD_S * 192, 192, 192, 0, LL, 1);
  seg(W_mlp,   wmlpb, NPAD_MLP * 192, 192, 192, 0, VOC, 1);
  k_convall<<<blk, 256, 0, stream>>>(tab);

  // --- 2: x time-mean (for q) ---
  k_xmean<<<BB * 6, 256, 0, stream>>>(x, xmbf);

  // --- 3: mega GEMM: st (fused sigmoid*tanh epilogue), ah, ag, q ---
  GSegTable gt;
  int gblk = 0, gi = 0;
  auto gseg = [&](const unsigned short* A, const unsigned short* B, float* C,
                  const float* bias, const float* aux, unsigned short* outbf,
                  int M, int N, int K, int nMblk, int nNblk, int emode) {
    gt.s[gi].A = A; gt.s[gi].B = B; gt.s[gi].C = C; gt.s[gi].bias = bias;
    gt.s[gi].aux = aux; gt.s[gi].outbf = outbf;
    gt.s[gi].M = M; gt.s[gi].Nout = N; gt.s[gi].K = K; gt.s[gi].nMblk = nMblk;
    gt.s[gi].blk0 = gblk; gt.s[gi].emode = emode;
    gblk += nMblk * nNblk; ++gi;
  };
  gseg(xh,   wsxh, nullptr, nullptr, cells, stbf, BT, HID, K2,  15, 3, 1);
  gseg(Hbf,  wahb, AH,      nullptr, nullptr, nullptr, BL, HID, HID, 13, 3, 0);
  gseg(Gbf,  wagb, AG,      nullptr, nullptr, nullptr, BL, HID, HID, 13, 3, 0);
  gseg(xmbf, waxb, qb,      nullptr, nullptr, nullptr, BB, HID, E2,  1,  3, 0);
  gt.s[4] = gt.s[3]; gt.s[4].blk0 = 0x7fffffff;
  gemm8p<true><<<gblk, 512, 65536, stream>>>(gt);

  // --- 4: switch ---
  k_switch<<<BL, 256, 0, stream>>>(AH, AG, qb, w_sw, H, G, Vbf, swout);

  // --- 5: skinny GEMMs (one segmented dispatch) ---
  SSegTable st;
  st.s[0] = SSeg{Vbf,   wvb, PV, BL, 64, HID, 25, 0};
  st.s[1] = SSeg{hidbf, wgb, PG, BT, 64, HID, 30, 25};
  st.s[2] = SSeg{stbf,  wsb, SS, BT, 64, HID, 30, 55};
  gemm_bt_seg<<<85, 256, 0, stream>>>(st);

  // --- 6: attention epilogue ---
  k_attn<<<BB * (TT / 4), 256, 0, stream>>>(PV, PG, SS, wh, stbf, Vbf, hiddens,
                                            alpha, beta, chh);

  // --- 7: scores GEMM (15x40 = 600 blocks, fp32+bias) ---
  GSegTable gs;
  gs.s[0] = GSeg{chh, wmlpb, scores, b_mlp, nullptr, nullptr, BT, VOC, HID, 15, 0, 0};
  for (int i = 1; i < NGSEG; ++i) { gs.s[i] = gs.s[0]; gs.s[i].blk0 = 0x7fffffff; }
  gemm8p<false><<<15 * 40, 512, 65536, stream>>>(gs);
}

// Round 10
// 346.646 us; speedup vs baseline: 4.3738x; 4.3738x over previous
//
#include <hip/hip_runtime.h>

#define BB 64
#define TT 60
#define LL 49
#define HID 768
#define E2 1536
#define K2 2304          // E2 + HID (concat for s_t GEMM)
#define VOC 10000
#define BT (BB*TT)      // 3840
#define BL (BB*LL)      // 3136
#define NPAD_MLP 10240
#define NPAD_S 128

typedef __bf16 bf16x8 __attribute__((ext_vector_type(8)));
typedef float f32x4 __attribute__((ext_vector_type(4)));

__device__ __forceinline__ unsigned short f2bf(float f) {
  union { float f; unsigned int u; } v; v.f = f;
  unsigned int u = v.u;
  return (unsigned short)((u + 0x7fffu + ((u >> 16) & 1u)) >> 16);  // RNE
}
__device__ __forceinline__ float bf2f(unsigned short h) {
  union { unsigned int u; float f; } v; v.u = ((unsigned int)h) << 16;
  return v.f;
}
__device__ __forceinline__ float fast_tanh(float x) {
  float e = __expf(2.f * x);
  return 1.f - 2.f / (e + 1.f);
}
__device__ __forceinline__ float fast_sigmoid(float x) {
  return 1.f / (1.f + __expf(-x));
}

// ---------------- fused convert with strided destination ----------------
#define NSEG 14
#define CHUNK4 2048
struct SegT {
  const float* src;
  unsigned short* dst;
  int n4;        // total vec4 elements (source-logical)
  int rl4;       // source row length in vec4
  int dstride4;  // dst row stride in vec4
  int dcol4;     // dst col offset in vec4
  int nrows;     // valid rows (mode 1)
  int mode;      // 0 plain, 1 pad-rows, 2 timestep-shift
  int blk0;
};
struct SegTable { SegT s[NSEG]; };

__global__ __launch_bounds__(256) void k_convall(SegTable tab) {
  int b = blockIdx.x;
  int si = 0;
#pragma unroll
  for (int i = 1; i < NSEG; ++i) si += (b >= tab.s[i].blk0);
  SegT sg = tab.s[si];
  int lb = b - sg.blk0;
  int end = (lb + 1) * CHUNK4; end = end < sg.n4 ? end : sg.n4;
  for (int i = lb * CHUNK4 + threadIdx.x; i < end; i += 256) {
    int row = i / sg.rl4, c = i - row * sg.rl4;
    ushort4 o; o.x = o.y = o.z = o.w = 0;
    if (sg.mode == 0) {
      float4 v = ((const float4*)sg.src)[i];
      o.x = f2bf(v.x); o.y = f2bf(v.y); o.z = f2bf(v.z); o.w = f2bf(v.w);
    } else if (sg.mode == 1) {
      if (row < sg.nrows) {
        float4 v = ((const float4*)sg.src)[i];
        o.x = f2bf(v.x); o.y = f2bf(v.y); o.z = f2bf(v.z); o.w = f2bf(v.w);
      }
    } else {  // timestep shift: row bt -> src row bt-1, zeros at t==0
      if (row % TT != 0) {
        float4 v = ((const float4*)sg.src)[i - sg.rl4];
        o.x = f2bf(v.x); o.y = f2bf(v.y); o.z = f2bf(v.z); o.w = f2bf(v.w);
      }
    }
    ((ushort4*)sg.dst)[(size_t)row * sg.dstride4 + sg.dcol4 + c] = o;
  }
}

// ---------------- k_xmean: xm[b,c] = bf16(mean_t x[b,t,c]) ----------------
__global__ __launch_bounds__(256) void k_xmean(const float* __restrict__ x,
                                               unsigned short* __restrict__ xm) {
  int b = blockIdx.x / 6;
  int c = (blockIdx.x % 6) * 256 + threadIdx.x;
  float s = 0.f;
  for (int t = 0; t < TT; ++t) s += x[((size_t)b * TT + t) * E2 + c];
  xm[(size_t)b * E2 + c] = f2bf(s * (1.f / 60.f));
}

// ---------------- segmented 128^2 2-phase GEMM (skinny N=64 GEMMs) ----------------
struct SSeg {
  const unsigned short* A; const unsigned short* B; float* C;
  int M, Nout, K, nMblk, blk0;
};
#define NSSEG 3
struct SSegTable { SSeg s[NSSEG]; };

__global__ __launch_bounds__(256) void gemm_bt_seg(SSegTable tab)
{
  __shared__ __attribute__((aligned(16))) unsigned short As[128*32];
  __shared__ __attribute__((aligned(16))) unsigned short Bs[128*32];
  const int tid  = threadIdx.x;
  const int lane = tid & 63;
  const int wave = tid >> 6;

  const int nwg = gridDim.x;
  const int id  = blockIdx.x;
  const int q = nwg >> 3, r = nwg & 7;
  const int xcd = id & 7, lo = id >> 3;
  const int wgid = (xcd < r ? xcd * (q + 1) : r * (q + 1) + (xcd - r) * q) + lo;

  int si = 0;
#pragma unroll
  for (int i = 1; i < NSSEG; ++i) si += (wgid >= tab.s[i].blk0);
  const SSeg sg = tab.s[si];
  const int lwg = wgid - sg.blk0;
  const int mb = lwg % sg.nMblk;
  const int nb = lwg / sg.nMblk;
  const int M = sg.M, Nout = sg.Nout, K = sg.K;
  const unsigned short* __restrict__ A  = sg.A;
  const unsigned short* __restrict__ Bw = sg.B;
  float* __restrict__ C = sg.C;
  const int m0 = mb * 128;
  const int n0 = nb * 128;
  const int wm = (wave >> 1) * 64;
  const int wn = (wave & 1) * 64;

  f32x4 acc[4][4];
#pragma unroll
  for (int i = 0; i < 4; ++i)
#pragma unroll
    for (int j = 0; j < 4; ++j) acc[i][j] = f32x4{0.f, 0.f, 0.f, 0.f};

  const int lrow = lane & 15;
  const int kb   = (lane >> 4) * 8;

  for (int k0 = 0; k0 < K; k0 += 32) {
    __syncthreads();
#pragma unroll
    for (int p = 0; p < 2; ++p) {
      int slot = p * 256 + wave * 64 + lane;
      int row = slot >> 2, c8 = slot & 3;
      int ar = m0 + row; ar = ar < M ? ar : (M - 1);
      const unsigned short* asrc = A + (size_t)ar * K + k0 + c8 * 8;
      __builtin_amdgcn_global_load_lds(
          (const __attribute__((address_space(1))) void*)asrc,
          (__attribute__((address_space(3))) void*)&As[(p * 256 + wave * 64) * 8],
          16, 0, 0);
      const unsigned short* bsrc = Bw + (size_t)(n0 + row) * K + k0 + c8 * 8;
      __builtin_amdgcn_global_load_lds(
          (const __attribute__((address_space(1))) void*)bsrc,
          (__attribute__((address_space(3))) void*)&Bs[(p * 256 + wave * 64) * 8],
          16, 0, 0);
    }
    __syncthreads();

    bf16x8 av[4], bv[4];
#pragma unroll
    for (int i = 0; i < 4; ++i)
      av[i] = *(const bf16x8*)&As[(wm + i * 16 + lrow) * 32 + kb];
#pragma unroll
    for (int j = 0; j < 4; ++j)
      bv[j] = *(const bf16x8*)&Bs[(wn + j * 16 + lrow) * 32 + kb];
#pragma unroll
    for (int i = 0; i < 4; ++i)
#pragma unroll
      for (int j = 0; j < 4; ++j)
        acc[i][j] = __builtin_amdgcn_mfma_f32_16x16x32_bf16(av[i], bv[j], acc[i][j], 0, 0, 0);
  }

  const int cr = (lane >> 4) * 4;
  const int cc = lane & 15;
#pragma unroll
  for (int i = 0; i < 4; ++i) {
    int row0 = m0 + wm + i * 16 + cr;
#pragma unroll
    for (int j = 0; j < 4; ++j) {
      int col = n0 + wn + j * 16 + cc;
      if (col < Nout) {
#pragma unroll
        for (int r2 = 0; r2 < 4; ++r2) {
          int row = row0 + r2;
          if (row < M) C[(size_t)row * Nout + col] = acc[i][j][r2];
        }
      }
    }
  }
}

// ---------------- 256^2 lean pipelined GEMM: BK=32, 2-buffer, 64KB -> 2 blk/CU ----------------
// launch_bounds(512,2): allocator gets 256-VGPR budget (R9's (512,4) cap of 128
// spilled acc to scratch -> 770us dispatches; R5/R6 at (512,2) allocate 128 arch
// VGPR, acc in unified AGPR half). 64KB LDS x2 = 128KB <= 160KB -> 2 blocks/CU.
// Tile kt uses buf c=kt&1. PH0(kt) stages B(kt+1)->buf c^1 (dead since barrier
// closing kt-1); PH1(kt) stages A(kt+2)->buf c (A(c) reads finished at PH0's
// closing barrier). VM2 at tile end drains tile kt+1's B (A(kt+1) drained one
// tile later with slack). Counted vmcnt, never 0 mid-loop.
// Swizzle (both-sides, rule #21): 16B-slot s' = s ^ ((row>>1)&3).
// LDS buf: A 16KB @ +0, B 16KB @ +16384, stride 32768.
// Epilogue modes: 0 = fp32 C + optional bias; 1 = bf16 sigmoid(acc)*tanh(aux).
#define BARR() do { asm volatile("" ::: "memory"); __builtin_amdgcn_s_barrier(); \
                    asm volatile("" ::: "memory"); } while (0)
#define VM2() asm volatile("s_waitcnt vmcnt(2)" ::: "memory")
#define VM0() asm volatile("s_waitcnt vmcnt(0)" ::: "memory")

#define STAGE_OP(bufi, op, kt) do {                                             \
  int k0_ = (kt) * 32;                                                          \
  _Pragma("unroll")                                                             \
  for (int l_ = 0; l_ < 2; ++l_) {                                              \
    int rr_ = l_ * 128 + sr0;                                                   \
    int ss_ = ssp ^ ((rr_ >> 1) & 3);                                           \
    int gr_;                                                                    \
    if (op) gr_ = n0 + rr_;                                                     \
    else    gr_ = CLAMP ? ((m0 + rr_) < M ? (m0 + rr_) : (M - 1)) : (m0 + rr_); \
    const unsigned short* src_ = ((op) ? Bw : Ap) + (size_t)gr_ * K + k0_ + ss_ * 8; \
    char* dst_ = smem + (bufi) * 32768 + (op) * 16384 + l_ * 8192 + w * 1024;   \
    __builtin_amdgcn_global_load_lds(                                           \
        (const __attribute__((address_space(1))) void*)src_,                    \
        (__attribute__((address_space(3))) void*)dst_, 16, 0, 0);               \
  }                                                                             \
} while (0)

#define LDA(bufi, row) (*(const bf16x8*)(smem + (bufi) * 32768 + (row) * 64 + (cg ^ (((row) >> 1) & 3)) * 16))
#define LDB(bufi, row) (*(const bf16x8*)(smem + (bufi) * 32768 + 16384 + (row) * 64 + (cg ^ (((row) >> 1) & 3)) * 16))

#define PH0(bufi, STAGE_STMT) do {                                              \
  STAGE_STMT;                                                                   \
  bf16x8 bfr0 = LDB(bufi, wn + lrow);                                           \
  bf16x8 bfr1 = LDB(bufi, wn + 16 + lrow);                                      \
  _Pragma("unroll")                                                             \
  for (int i_ = 0; i_ < 8; ++i_) afr[i_] = LDA(bufi, wm + i_ * 16 + lrow);      \
  __builtin_amdgcn_s_setprio(1);                                                \
  _Pragma("unroll")                                                             \
  for (int i_ = 0; i_ < 8; ++i_) {                                              \
    acc[i_][0] = __builtin_amdgcn_mfma_f32_16x16x32_bf16(afr[i_], bfr0, acc[i_][0], 0, 0, 0); \
    acc[i_][1] = __builtin_amdgcn_mfma_f32_16x16x32_bf16(afr[i_], bfr1, acc[i_][1], 0, 0, 0); \
  }                                                                             \
  __builtin_amdgcn_s_setprio(0);                                                \
  BARR();                                                                       \
} while (0)

#define PH1(bufi, STAGE_STMT, VM_STMT) do {                                     \
  STAGE_STMT;                                                                   \
  bf16x8 bfr0 = LDB(bufi, wn + 32 + lrow);                                      \
  bf16x8 bfr1 = LDB(bufi, wn + 48 + lrow);                                      \
  __builtin_amdgcn_s_setprio(1);                                                \
  _Pragma("unroll")                                                             \
  for (int i_ = 0; i_ < 8; ++i_) {                                              \
    acc[i_][2] = __builtin_amdgcn_mfma_f32_16x16x32_bf16(afr[i_], bfr0, acc[i_][2], 0, 0, 0); \
    acc[i_][3] = __builtin_amdgcn_mfma_f32_16x16x32_bf16(afr[i_], bfr1, acc[i_][3], 0, 0, 0); \
  }                                                                             \
  __builtin_amdgcn_s_setprio(0);                                                \
  VM_STMT;                                                                      \
  BARR();                                                                       \
} while (0)

struct GSeg {
  const unsigned short* A; const unsigned short* B; float* C;
  const float* bias;
  const float* aux;           // cells (emode 1)
  unsigned short* outbf;      // bf16 output (emode 1)
  int M, Nout, K, nMblk, blk0, emode;
};
#define NGSEG 5
struct GSegTable { GSeg s[NGSEG]; };

template <bool CLAMP>
__global__ __launch_bounds__(512, 2) void gemm8p(GSegTable tab)
{
  extern __shared__ char smem[];
  const int tid  = threadIdx.x;
  const int lane = tid & 63;
  const int w    = tid >> 6;              // 0..7
  const int lrow = lane & 15;
  const int cg   = lane >> 4;             // logical 16B slot
  const int sr0  = w * 16 + (lane >> 2);  // stage row (l_=0)
  const int ssp  = lane & 3;              // physical 16B slot

  const int nwg = gridDim.x;
  const int id  = blockIdx.x;
  const int q = nwg >> 3, r = nwg & 7;
  const int xcd = id & 7, lo = id >> 3;
  const int wgid = (xcd < r ? xcd * (q + 1) : r * (q + 1) + (xcd - r) * q) + lo;

  int si = 0;
#pragma unroll
  for (int i = 1; i < NGSEG; ++i) si += (wgid >= tab.s[i].blk0);
  const GSeg sg = tab.s[si];
  const int lwg = wgid - sg.blk0;
  const int mb = lwg % sg.nMblk;
  const int nb = lwg / sg.nMblk;
  const int M = sg.M, Nout = sg.Nout, K = sg.K;
  const unsigned short* __restrict__ Ap = sg.A;
  const unsigned short* __restrict__ Bw = sg.B;

  const int m0 = mb * 256;
  const int n0 = nb * 256;
  const int wm = (w >> 2) * 128;   // 0 or 128
  const int wn = (w & 3) * 64;     // 0,64,128,192

  f32x4 acc[8][4];
#pragma unroll
  for (int i = 0; i < 8; ++i)
#pragma unroll
    for (int j = 0; j < 4; ++j) acc[i][j] = f32x4{0.f, 0.f, 0.f, 0.f};
  bf16x8 afr[8];

  const int NT = K >> 5;  // K/32, >= 3

  // prologue: A(0),B(0),A(1) = 6 loads; VM2 -> tile0's 4 arrived
  STAGE_OP(0, 0, 0);
  STAGE_OP(0, 1, 0);
  STAGE_OP(1, 0, 1);
  VM2();
  BARR();

  for (int kt = 0; kt < NT - 2; ++kt) {
    const int c = kt & 1;
    PH0(c, STAGE_OP(c ^ 1, 1, kt + 1));        // B(kt+1) -> dead buf
    PH1(c, STAGE_OP(c, 0, kt + 2), VM2(););    // A(kt+2) -> current buf (A reads done)
  }
  {
    const int c = (NT - 2) & 1;
    PH0(c, STAGE_OP(c ^ 1, 1, NT - 1));
    PH1(c, ;, VM0(););
  }
  {
    const int c = (NT - 1) & 1;
    PH0(c, ;);
    PH1(c, ;, ;);
  }

  // epilogue: C/D layout col=lane&15, row=(lane>>4)*4+reg
  if (sg.emode == 0) {
    float* __restrict__ C = sg.C;
    const float* __restrict__ bias = sg.bias;
#pragma unroll
    for (int i = 0; i < 8; ++i) {
      int row0 = m0 + wm + i * 16 + (lane >> 4) * 4;
#pragma unroll
      for (int j = 0; j < 4; ++j) {
        int col = n0 + wn + j * 16 + (lane & 15);
        if (col < Nout) {
          float badd = bias ? bias[col] : 0.f;
#pragma unroll
          for (int r2 = 0; r2 < 4; ++r2) {
            int row = row0 + r2;
            if (!CLAMP || row < M) C[(size_t)row * Nout + col] = acc[i][j][r2] + badd;
          }
        }
      }
    }
  } else {
    // s_t epilogue: bf16( sigmoid(acc) * tanh(cells) )
    const float* __restrict__ cells = sg.aux;
    unsigned short* __restrict__ ob = sg.outbf;
#pragma unroll
    for (int i = 0; i < 8; ++i) {
      int row0 = m0 + wm + i * 16 + (lane >> 4) * 4;
#pragma unroll
      for (int j = 0; j < 4; ++j) {
        int col = n0 + wn + j * 16 + (lane & 15);
        if (col < Nout) {
#pragma unroll
          for (int r2 = 0; r2 < 4; ++r2) {
            int row = row0 + r2;
            if (!CLAMP || row < M) {
              float cv = cells[(size_t)row * Nout + col];
              ob[(size_t)row * Nout + col] = f2bf(fast_sigmoid(acc[i][j][r2]) * fast_tanh(cv));
            }
          }
        }
      }
    }
  }
}

// ---------------- E3: switch softmax + V ----------------
__global__ __launch_bounds__(256) void k_switch(
    const float* __restrict__ AH, const float* __restrict__ AG,
    const float* __restrict__ q, const float* __restrict__ wsw,
    const float* __restrict__ H, const float* __restrict__ G,
    unsigned short* __restrict__ Vbf, float* __restrict__ sw_out)
{
  int bl = blockIdx.x;
  int b = bl / LL;
  int tid = threadIdx.x;
  float aH = 0.f, aG = 0.f;
  for (int h = tid; h < HID; h += 256) {
    float qv = q[b * HID + h], w = wsw[h];
    aH += fast_tanh(AH[(size_t)bl * HID + h] + qv) * w;
    aG += fast_tanh(AG[(size_t)bl * HID + h] + qv) * w;
  }
#pragma unroll
  for (int off = 32; off > 0; off >>= 1) {
    aH += __shfl_down(aH, off);
    aG += __shfl_down(aG, off);
  }
  __shared__ float redH[4], redG[4];
  int lane = tid & 63, wave = tid >> 6;
  if (lane == 0) { redH[wave] = aH; redG[wave] = aG; }
  __syncthreads();
  float sH = redH[0] + redH[1] + redH[2] + redH[3];
  float sG = redG[0] + redG[1] + redG[2] + redG[3];
  float m = fmaxf(sH, sG);
  float e0 = __expf(sH - m), e1 = __expf(sG - m);
  float inv = 1.f / (e0 + e1);
  float sw0 = e0 * inv, sw1 = e1 * inv;
  if (tid == 0) { sw_out[bl * 2] = sw0; sw_out[bl * 2 + 1] = sw1; }
  for (int h = tid; h < HID; h += 256) {
    float v = sw0 * H[(size_t)bl * HID + h] + sw1 * G[(size_t)bl * HID + h];
    Vbf[(size_t)bl * HID + h] = f2bf(v);
  }
}

// ---------------- E4: z_t/z_s -> alpha/beta -> c_hat+hiddens ----------------
__global__ __launch_bounds__(256) void k_attn(
    const float* __restrict__ PV, const float* __restrict__ PG,
    const float* __restrict__ SS, const float* __restrict__ wh,
    const unsigned short* __restrict__ stbf, const unsigned short* __restrict__ Vbf,
    const float* __restrict__ hiddens,
    float* __restrict__ alpha_out, float* __restrict__ beta_out,
    unsigned short* __restrict__ chh)
{
  const int TG = 4;
  int b  = blockIdx.x / (TT / TG);
  int t0 = (blockIdx.x % (TT / TG)) * TG;
  int tid = threadIdx.x;
  __shared__ float pg_s[TG][LL], wh_s[LL], zz[TG][LL + 1], alpha_s[TG][LL], beta_sh[TG];

  if (tid < LL) wh_s[tid] = wh[tid];
  if (tid < TG * LL) {
    int tt = tid / LL, k = tid - tt * LL;
    pg_s[tt][k] = PG[(size_t)(b * TT + t0 + tt) * 64 + k];
  }
  __syncthreads();

  if (tid < TG * (LL + 1)) {
    int tt = tid / (LL + 1), l = tid - tt * (LL + 1);
    const float* src = (l < LL) ? &PV[((size_t)b * LL + l) * 64]
                                : &SS[(size_t)(b * TT + t0 + tt) * 64];
    float acc = 0.f;
    for (int k = 0; k < LL; ++k) acc += fast_tanh(src[k] + pg_s[tt][k]) * wh_s[k];
    zz[tt][l] = acc;
  }
  __syncthreads();

  if (tid < TG) {
    int tt = tid, bt = b * TT + t0 + tt;
    float mx = -1e30f;
    for (int l = 0; l < LL; ++l) mx = fmaxf(mx, zz[tt][l]);
    float sum = 0.f;
    for (int l = 0; l < LL; ++l) { float e = __expf(zz[tt][l] - mx); alpha_s[tt][l] = e; sum += e; }
    float inv = 1.f / sum;
    for (int l = 0; l < LL; ++l) {
      alpha_s[tt][l] *= inv;
      alpha_out[(size_t)bt * LL + l] = alpha_s[tt][l];
    }
    float mx2 = fmaxf(mx, zz[tt][LL]);
    float s2 = 0.f;
    for (int l = 0; l <= LL; ++l) s2 += __expf(zz[tt][l] - mx2);
    float bet = __expf(zz[tt][LL] - mx2) / s2;
    beta_sh[tt] = bet;
    beta_out[bt] = bet;
  }
  __syncthreads();

  for (int h = tid; h < HID; h += 256) {
    float ct[TG] = {0.f, 0.f, 0.f, 0.f};
    for (int l = 0; l < LL; ++l) {
      float v = bf2f(Vbf[((size_t)b * LL + l) * HID + h]);
#pragma unroll
      for (int tt = 0; tt < TG; ++tt) ct[tt] += alpha_s[tt][l] * v;
    }
#pragma unroll
    for (int tt = 0; tt < TG; ++tt) {
      int bt = b * TT + t0 + tt;
      float bet = beta_sh[tt];
      float s = bf2f(stbf[(size_t)bt * HID + h]);
      float chat = bet * s + (1.f - bet) * ct[tt];
      chh[(size_t)bt * HID + h] = f2bf(chat + hiddens[(size_t)bt * HID + h]);
    }
  }
}

// ---------------- launcher ----------------
extern "C" void kernel_launch(void* const* d_in, const int* in_sizes, int n_in,
                              void* d_out, int out_size, void* d_ws, size_t ws_size,
                              hipStream_t stream)
{
  const float* x       = (const float*)d_in[0];
  const float* hiddens = (const float*)d_in[1];
  const float* cells   = (const float*)d_in[2];
  const float* G       = (const float*)d_in[3];
  const float* H       = (const float*)d_in[4];
  const float* W_sx    = (const float*)d_in[5];
  const float* W_sh    = (const float*)d_in[6];
  const float* W_ax    = (const float*)d_in[7];
  const float* W_ah    = (const float*)d_in[8];
  const float* W_ag    = (const float*)d_in[9];
  const float* w_sw    = (const float*)d_in[10];
  const float* Wv      = (const float*)d_in[11];
  const float* Wg      = (const float*)d_in[12];
  const float* Ws      = (const float*)d_in[13];
  const float* wh      = (const float*)d_in[14];
  const float* W_mlp   = (const float*)d_in[15];
  const float* b_mlp   = (const float*)d_in[16];

  float* scores = (float*)d_out;
  float* alpha  = scores + (size_t)BT * VOC;
  float* beta   = alpha + (size_t)BT * LL;
  float* swout  = beta + BT;

  char* wsp = (char*)d_ws;
  size_t off = 0;
  auto alloc = [&](size_t bytes) -> char* {
    char* p = wsp + off;
    off += (bytes + 255) & ~(size_t)255;
    return p;
  };

  unsigned short* xh     = (unsigned short*)alloc((size_t)BT * K2 * 2);   // [x | hprev]
  unsigned short* wsxh   = (unsigned short*)alloc((size_t)HID * K2 * 2);  // [W_sx | W_sh]
  unsigned short* waxb   = (unsigned short*)alloc((size_t)HID * E2 * 2);
  unsigned short* wahb   = (unsigned short*)alloc((size_t)HID * HID * 2);
  unsigned short* wagb   = (unsigned short*)alloc((size_t)HID * HID * 2);
  unsigned short* Hbf    = (unsigned short*)alloc((size_t)BL * HID * 2);
  unsigned short* Gbf    = (unsigned short*)alloc((size_t)BL * HID * 2);
  unsigned short* hidbf  = (unsigned short*)alloc((size_t)BT * HID * 2);
  unsigned short* wvb    = (unsigned short*)alloc((size_t)NPAD_S * HID * 2);
  unsigned short* wgb    = (unsigned short*)alloc((size_t)NPAD_S * HID * 2);
  unsigned short* wsb    = (unsigned short*)alloc((size_t)NPAD_S * HID * 2);
  unsigned short* wmlpb  = (unsigned short*)alloc((size_t)NPAD_MLP * HID * 2);
  unsigned short* Vbf    = (unsigned short*)alloc((size_t)BL * HID * 2);
  unsigned short* stbf   = (unsigned short*)alloc((size_t)BT * HID * 2);
  unsigned short* chh    = (unsigned short*)alloc((size_t)BT * HID * 2);
  unsigned short* xmbf   = (unsigned short*)alloc((size_t)BB * E2 * 2);
  float* AH = (float*)alloc((size_t)BL * HID * 4);
  float* AG = (float*)alloc((size_t)BL * HID * 4);
  float* qb = (float*)alloc((size_t)BB * HID * 4);
  float* PV = (float*)alloc((size_t)BL * 64 * 4);
  float* PG = (float*)alloc((size_t)BT * 64 * 4);
  float* SS = (float*)alloc((size_t)BT * 64 * 4);
  (void)ws_size; (void)in_sizes; (void)n_in; (void)out_size;

  // --- 1: fused converts (strided-dst) ---
  SegTable tab;
  int blk = 0, si = 0;
  auto seg = [&](const float* s, unsigned short* d, int n4, int rl4, int dstride4,
                 int dcol4, int nrows, int mode) {
    tab.s[si].src = s; tab.s[si].dst = d; tab.s[si].n4 = n4; tab.s[si].rl4 = rl4;
    tab.s[si].dstride4 = dstride4; tab.s[si].dcol4 = dcol4;
    tab.s[si].nrows = nrows; tab.s[si].mode = mode; tab.s[si].blk0 = blk;
    blk += (n4 + CHUNK4 - 1) / CHUNK4; ++si;
  };
  seg(W_sx,    wsxh,  HID * 384, 384, 576, 0,   0, 0);
  seg(W_sh,    wsxh,  HID * 192, 192, 576, 384, 0, 0);
  seg(x,       xh,    BT * 384,  384, 576, 0,   0, 0);
  seg(hiddens, xh,    BT * 192,  192, 576, 384, 0, 2);   // shifted h_{t-1}
  seg(W_ax,    waxb,  HID * 384, 384, 384, 0,   0, 0);
  seg(W_ah,    wahb,  HID * 192, 192, 192, 0,   0, 0);
  seg(W_ag,    wagb,  HID * 192, 192, 192, 0,   0, 0);
  seg(H,       Hbf,   BL * 192,  192, 192, 0,   0, 0);
  seg(G,       Gbf,   BL * 192,  192, 192, 0,   0, 0);
  seg(hiddens, hidbf, BT * 192,  192, 192, 0,   0, 0);
  seg(Wv,      wvb,   NPAD_S * 192, 192, 192, 0, LL, 1);
  seg(Wg,      wgb,   NPAD_S * 192, 192, 192, 0, LL, 1);
  seg(Ws,      wsb,   NPAD_S * 192, 192, 192, 0, LL, 1);
  seg(W_mlp,   wmlpb, NPAD_MLP * 192, 192, 192, 0, VOC, 1);
  k_convall<<<blk, 256, 0, stream>>>(tab);

  // --- 2: x time-mean (for q) ---
  k_xmean<<<BB * 6, 256, 0, stream>>>(x, xmbf);

  // --- 3: mega GEMM: st (fused sigmoid*tanh epilogue), ah, ag, q ---
  GSegTable gt;
  int gblk = 0, gi = 0;
  auto gseg = [&](const unsigned short* A, const unsigned short* B, float* C,
                  const float* bias, const float* aux, unsigned short* outbf,
                  int M, int N, int K, int nMblk, int nNblk, int emode) {
    gt.s[gi].A = A; gt.s[gi].B = B; gt.s[gi].C = C; gt.s[gi].bias = bias;
    gt.s[gi].aux = aux; gt.s[gi].outbf = outbf;
    gt.s[gi].M = M; gt.s[gi].Nout = N; gt.s[gi].K = K; gt.s[gi].nMblk = nMblk;
    gt.s[gi].blk0 = gblk; gt.s[gi].emode = emode;
    gblk += nMblk * nNblk; ++gi;
  };
  gseg(xh,   wsxh, nullptr, nullptr, cells, stbf, BT, HID, K2,  15, 3, 1);
  gseg(Hbf,  wahb, AH,      nullptr, nullptr, nullptr, BL, HID, HID, 13, 3, 0);
  gseg(Gbf,  wagb, AG,      nullptr, nullptr, nullptr, BL, HID, HID, 13, 3, 0);
  gseg(xmbf, waxb, qb,      nullptr, nullptr, nullptr, BB, HID, E2,  1,  3, 0);
  gt.s[4] = gt.s[3]; gt.s[4].blk0 = 0x7fffffff;
  gemm8p<true><<<gblk, 512, 65536, stream>>>(gt);

  // --- 4: switch ---
  k_switch<<<BL, 256, 0, stream>>>(AH, AG, qb, w_sw, H, G, Vbf, swout);

  // --- 5: skinny GEMMs (one segmented dispatch) ---
  SSegTable st;
  st.s[0] = SSeg{Vbf,   wvb, PV, BL, 64, HID, 25, 0};
  st.s[1] = SSeg{hidbf, wgb, PG, BT, 64, HID, 30, 25};
  st.s[2] = SSeg{stbf,  wsb, SS, BT, 64, HID, 30, 55};
  gemm_bt_seg<<<85, 256, 0, stream>>>(st);

  // --- 6: attention epilogue ---
  k_attn<<<BB * (TT / 4), 256, 0, stream>>>(PV, PG, SS, wh, stbf, Vbf, hiddens,
                                            alpha, beta, chh);

  // --- 7: scores GEMM (15x40 = 600 blocks, fp32+bias) ---
  GSegTable gs;
  gs.s[0] = GSeg{chh, wmlpb, scores, b_mlp, nullptr, nullptr, BT, VOC, HID, 15, 0, 0};
  for (int i = 1; i < NGSEG; ++i) { gs.s[i] = gs.s[0]; gs.s[i].blk0 = 0x7fffffff; }
  gemm8p<false><<<15 * 40, 512, 65536, stream>>>(gs);
}

// Round 11
// 325.266 us; speedup vs baseline: 4.6613x; 1.0657x over previous
//
#include <hip/hip_runtime.h>

#define BB 64
#define TT 60
#define LL 49
#define HID 768
#define E2 1536
#define K2 2304          // E2 + HID (concat for s_t GEMM)
#define VOC 10000
#define BT (BB*TT)      // 3840
#define BL (BB*LL)      // 3136
#define NPAD_MLP 10240
#define NPAD_S 128

typedef __bf16 bf16x8 __attribute__((ext_vector_type(8)));
typedef float f32x4 __attribute__((ext_vector_type(4)));

__device__ __forceinline__ unsigned short f2bf(float f) {
  union { float f; unsigned int u; } v; v.f = f;
  unsigned int u = v.u;
  return (unsigned short)((u + 0x7fffu + ((u >> 16) & 1u)) >> 16);  // RNE
}
__device__ __forceinline__ float bf2f(unsigned short h) {
  union { unsigned int u; float f; } v; v.u = ((unsigned int)h) << 16;
  return v.f;
}
__device__ __forceinline__ float fast_tanh(float x) {
  float e = __expf(2.f * x);
  return 1.f - 2.f / (e + 1.f);
}
__device__ __forceinline__ float fast_sigmoid(float x) {
  return 1.f / (1.f + __expf(-x));
}

// ---------------- fused convert with strided destination ----------------
#define NSEG 14
#define CHUNK4 2048
struct SegT {
  const float* src;
  unsigned short* dst;
  int n4;        // total vec4 elements (source-logical)
  int rl4;       // source row length in vec4
  int dstride4;  // dst row stride in vec4
  int dcol4;     // dst col offset in vec4
  int nrows;     // valid rows (mode 1)
  int mode;      // 0 plain, 1 pad-rows, 2 timestep-shift
  int blk0;
};
struct SegTable { SegT s[NSEG]; };

__global__ __launch_bounds__(256) void k_convall(SegTable tab) {
  int b = blockIdx.x;
  int si = 0;
#pragma unroll
  for (int i = 1; i < NSEG; ++i) si += (b >= tab.s[i].blk0);
  SegT sg = tab.s[si];
  int lb = b - sg.blk0;
  int end = (lb + 1) * CHUNK4; end = end < sg.n4 ? end : sg.n4;
  for (int i = lb * CHUNK4 + threadIdx.x; i < end; i += 256) {
    int row = i / sg.rl4, c = i - row * sg.rl4;
    ushort4 o; o.x = o.y = o.z = o.w = 0;
    if (sg.mode == 0) {
      float4 v = ((const float4*)sg.src)[i];
      o.x = f2bf(v.x); o.y = f2bf(v.y); o.z = f2bf(v.z); o.w = f2bf(v.w);
    } else if (sg.mode == 1) {
      if (row < sg.nrows) {
        float4 v = ((const float4*)sg.src)[i];
        o.x = f2bf(v.x); o.y = f2bf(v.y); o.z = f2bf(v.z); o.w = f2bf(v.w);
      }
    } else {  // timestep shift: row bt -> src row bt-1, zeros at t==0
      if (row % TT != 0) {
        float4 v = ((const float4*)sg.src)[i - sg.rl4];
        o.x = f2bf(v.x); o.y = f2bf(v.y); o.z = f2bf(v.z); o.w = f2bf(v.w);
      }
    }
    ((ushort4*)sg.dst)[(size_t)row * sg.dstride4 + sg.dcol4 + c] = o;
  }
}

// ---------------- k_xmean: xm[b,c] = bf16(mean_t x[b,t,c]) ----------------
__global__ __launch_bounds__(256) void k_xmean(const float* __restrict__ x,
                                               unsigned short* __restrict__ xm) {
  int b = blockIdx.x / 6;
  int c = (blockIdx.x % 6) * 256 + threadIdx.x;
  float s = 0.f;
  for (int t = 0; t < TT; ++t) s += x[((size_t)b * TT + t) * E2 + c];
  xm[(size_t)b * E2 + c] = f2bf(s * (1.f / 60.f));
}

// ---------------- segmented 128^2 2-phase GEMM (mega + skinny) ----------------
// 16KB LDS, ~70 VGPR -> 3-4 blocks/CU. Grid-parallelism workhorse for
// mid-size GEMMs (the 256^2 pipeline needs >=500 blocks to pay; these have
// 126-486). Epilogue modes: 0 = fp32 (+bias); 1 = bf16 sigmoid(acc)*tanh(aux).
struct SSeg {
  const unsigned short* A; const unsigned short* B;
  float* C; const float* bias; const float* aux; unsigned short* outbf;
  int M, Nout, K, nMblk, blk0, emode;
};
#define NSSEG 4
struct SSegTable { SSeg s[NSSEG]; };

__global__ __launch_bounds__(256) void gemm_bt_seg(SSegTable tab)
{
  __shared__ __attribute__((aligned(16))) unsigned short As[128*32];
  __shared__ __attribute__((aligned(16))) unsigned short Bs[128*32];
  const int tid  = threadIdx.x;
  const int lane = tid & 63;
  const int wave = tid >> 6;

  const int nwg = gridDim.x;
  const int id  = blockIdx.x;
  const int q = nwg >> 3, r = nwg & 7;
  const int xcd = id & 7, lo = id >> 3;
  const int wgid = (xcd < r ? xcd * (q + 1) : r * (q + 1) + (xcd - r) * q) + lo;

  int si = 0;
#pragma unroll
  for (int i = 1; i < NSSEG; ++i) si += (wgid >= tab.s[i].blk0);
  const SSeg sg = tab.s[si];
  const int lwg = wgid - sg.blk0;
  const int mb = lwg % sg.nMblk;
  const int nb = lwg / sg.nMblk;
  const int M = sg.M, Nout = sg.Nout, K = sg.K;
  const unsigned short* __restrict__ A  = sg.A;
  const unsigned short* __restrict__ Bw = sg.B;
  const int m0 = mb * 128;
  const int n0 = nb * 128;
  const int wm = (wave >> 1) * 64;
  const int wn = (wave & 1) * 64;

  f32x4 acc[4][4];
#pragma unroll
  for (int i = 0; i < 4; ++i)
#pragma unroll
    for (int j = 0; j < 4; ++j) acc[i][j] = f32x4{0.f, 0.f, 0.f, 0.f};

  const int lrow = lane & 15;
  const int kb   = (lane >> 4) * 8;

  for (int k0 = 0; k0 < K; k0 += 32) {
    __syncthreads();
#pragma unroll
    for (int p = 0; p < 2; ++p) {
      int slot = p * 256 + wave * 64 + lane;
      int row = slot >> 2, c8 = slot & 3;
      int ar = m0 + row; ar = ar < M ? ar : (M - 1);
      const unsigned short* asrc = A + (size_t)ar * K + k0 + c8 * 8;
      __builtin_amdgcn_global_load_lds(
          (const __attribute__((address_space(1))) void*)asrc,
          (__attribute__((address_space(3))) void*)&As[(p * 256 + wave * 64) * 8],
          16, 0, 0);
      const unsigned short* bsrc = Bw + (size_t)(n0 + row) * K + k0 + c8 * 8;
      __builtin_amdgcn_global_load_lds(
          (const __attribute__((address_space(1))) void*)bsrc,
          (__attribute__((address_space(3))) void*)&Bs[(p * 256 + wave * 64) * 8],
          16, 0, 0);
    }
    __syncthreads();

    bf16x8 av[4], bv[4];
#pragma unroll
    for (int i = 0; i < 4; ++i)
      av[i] = *(const bf16x8*)&As[(wm + i * 16 + lrow) * 32 + kb];
#pragma unroll
    for (int j = 0; j < 4; ++j)
      bv[j] = *(const bf16x8*)&Bs[(wn + j * 16 + lrow) * 32 + kb];
#pragma unroll
    for (int i = 0; i < 4; ++i)
#pragma unroll
      for (int j = 0; j < 4; ++j)
        acc[i][j] = __builtin_amdgcn_mfma_f32_16x16x32_bf16(av[i], bv[j], acc[i][j], 0, 0, 0);
  }

  const int cr = (lane >> 4) * 4;
  const int cc = lane & 15;
  if (sg.emode == 0) {
    float* __restrict__ C = sg.C;
    const float* __restrict__ bias = sg.bias;
#pragma unroll
    for (int i = 0; i < 4; ++i) {
      int row0 = m0 + wm + i * 16 + cr;
#pragma unroll
      for (int j = 0; j < 4; ++j) {
        int col = n0 + wn + j * 16 + cc;
        if (col < Nout) {
          float badd = bias ? bias[col] : 0.f;
#pragma unroll
          for (int r2 = 0; r2 < 4; ++r2) {
            int row = row0 + r2;
            if (row < M) C[(size_t)row * Nout + col] = acc[i][j][r2] + badd;
          }
        }
      }
    }
  } else {
    // s_t epilogue: bf16( sigmoid(acc) * tanh(cells) )
    const float* __restrict__ cells = sg.aux;
    unsigned short* __restrict__ ob = sg.outbf;
#pragma unroll
    for (int i = 0; i < 4; ++i) {
      int row0 = m0 + wm + i * 16 + cr;
#pragma unroll
      for (int j = 0; j < 4; ++j) {
        int col = n0 + wn + j * 16 + cc;
        if (col < Nout) {
#pragma unroll
          for (int r2 = 0; r2 < 4; ++r2) {
            int row = row0 + r2;
            if (row < M) {
              float cv = cells[(size_t)row * Nout + col];
              ob[(size_t)row * Nout + col] = f2bf(fast_sigmoid(acc[i][j][r2]) * fast_tanh(cv));
            }
          }
        }
      }
    }
  }
}

// ---------------- 256^2 lean pipelined GEMM (scores): BK=32, 2-buffer, 64KB ----------------
// launch_bounds(512,2): 128 arch-VGPR (acc in unified AGPR half, no spill —
// R10-verified); 64KB LDS x2 = 128KB -> 2 blocks/CU. Tile kt uses buf c=kt&1.
// PH0(kt) stages B(kt+1)->buf c^1 (dead); PH1(kt) stages A(kt+2)->buf c.
// VM2 at tile end (counted, never 0 mid-loop).
// Swizzle (both-sides, rule #21): 16B-slot s' = s ^ ((row>>1)&3).
#define BARR() do { asm volatile("" ::: "memory"); __builtin_amdgcn_s_barrier(); \
                    asm volatile("" ::: "memory"); } while (0)
#define VM2() asm volatile("s_waitcnt vmcnt(2)" ::: "memory")
#define VM0() asm volatile("s_waitcnt vmcnt(0)" ::: "memory")

#define STAGE_OP(bufi, op, kt) do {                                             \
  int k0_ = (kt) * 32;                                                          \
  _Pragma("unroll")                                                             \
  for (int l_ = 0; l_ < 2; ++l_) {                                              \
    int rr_ = l_ * 128 + sr0;                                                   \
    int ss_ = ssp ^ ((rr_ >> 1) & 3);                                           \
    int gr_ = (op) ? (n0 + rr_) : (m0 + rr_);                                   \
    const unsigned short* src_ = ((op) ? Bw : Ap) + (size_t)gr_ * K + k0_ + ss_ * 8; \
    char* dst_ = smem + (bufi) * 32768 + (op) * 16384 + l_ * 8192 + w * 1024;   \
    __builtin_amdgcn_global_load_lds(                                           \
        (const __attribute__((address_space(1))) void*)src_,                    \
        (__attribute__((address_space(3))) void*)dst_, 16, 0, 0);               \
  }                                                                             \
} while (0)

#define LDA(bufi, row) (*(const bf16x8*)(smem + (bufi) * 32768 + (row) * 64 + (cg ^ (((row) >> 1) & 3)) * 16))
#define LDB(bufi, row) (*(const bf16x8*)(smem + (bufi) * 32768 + 16384 + (row) * 64 + (cg ^ (((row) >> 1) & 3)) * 16))

#define PH0(bufi, STAGE_STMT) do {                                              \
  STAGE_STMT;                                                                   \
  bf16x8 bfr0 = LDB(bufi, wn + lrow);                                           \
  bf16x8 bfr1 = LDB(bufi, wn + 16 + lrow);                                      \
  _Pragma("unroll")                                                             \
  for (int i_ = 0; i_ < 8; ++i_) afr[i_] = LDA(bufi, wm + i_ * 16 + lrow);      \
  __builtin_amdgcn_s_setprio(1);                                                \
  _Pragma("unroll")                                                             \
  for (int i_ = 0; i_ < 8; ++i_) {                                              \
    acc[i_][0] = __builtin_amdgcn_mfma_f32_16x16x32_bf16(afr[i_], bfr0, acc[i_][0], 0, 0, 0); \
    acc[i_][1] = __builtin_amdgcn_mfma_f32_16x16x32_bf16(afr[i_], bfr1, acc[i_][1], 0, 0, 0); \
  }                                                                             \
  __builtin_amdgcn_s_setprio(0);                                                \
  BARR();                                                                       \
} while (0)

#define PH1(bufi, STAGE_STMT, VM_STMT) do {                                     \
  STAGE_STMT;                                                                   \
  bf16x8 bfr0 = LDB(bufi, wn + 32 + lrow);                                      \
  bf16x8 bfr1 = LDB(bufi, wn + 48 + lrow);                                      \
  __builtin_amdgcn_s_setprio(1);                                                \
  _Pragma("unroll")                                                             \
  for (int i_ = 0; i_ < 8; ++i_) {                                              \
    acc[i_][2] = __builtin_amdgcn_mfma_f32_16x16x32_bf16(afr[i_], bfr0, acc[i_][2], 0, 0, 0); \
    acc[i_][3] = __builtin_amdgcn_mfma_f32_16x16x32_bf16(afr[i_], bfr1, acc[i_][3], 0, 0, 0); \
  }                                                                             \
  __builtin_amdgcn_s_setprio(0);                                                \
  VM_STMT;                                                                      \
  BARR();                                                                       \
} while (0)

__global__ __launch_bounds__(512, 2) void gemm_sc(
    const unsigned short* __restrict__ Ap,
    const unsigned short* __restrict__ Bw,
    float* __restrict__ C,
    const float* __restrict__ bias,
    int M, int Nout, int K, int nMblk)
{
  extern __shared__ char smem[];
  const int tid  = threadIdx.x;
  const int lane = tid & 63;
  const int w    = tid >> 6;              // 0..7
  const int lrow = lane & 15;
  const int cg   = lane >> 4;             // logical 16B slot
  const int sr0  = w * 16 + (lane >> 2);  // stage row (l_=0)
  const int ssp  = lane & 3;              // physical 16B slot

  const int nwg = gridDim.x;
  const int id  = blockIdx.x;
  const int q = nwg >> 3, r = nwg & 7;
  const int xcd = id & 7, lo = id >> 3;
  const int wgid = (xcd < r ? xcd * (q + 1) : r * (q + 1) + (xcd - r) * q) + lo;
  const int mb = wgid % nMblk;
  const int nb = wgid / nMblk;

  const int m0 = mb * 256;
  const int n0 = nb * 256;
  const int wm = (w >> 2) * 128;   // 0 or 128
  const int wn = (w & 3) * 64;     // 0,64,128,192

  f32x4 acc[8][4];
#pragma unroll
  for (int i = 0; i < 8; ++i)
#pragma unroll
    for (int j = 0; j < 4; ++j) acc[i][j] = f32x4{0.f, 0.f, 0.f, 0.f};
  bf16x8 afr[8];

  const int NT = K >> 5;  // K/32, >= 3

  // prologue: A(0),B(0),A(1) = 6 loads; VM2 -> tile0's 4 arrived
  STAGE_OP(0, 0, 0);
  STAGE_OP(0, 1, 0);
  STAGE_OP(1, 0, 1);
  VM2();
  BARR();

  for (int kt = 0; kt < NT - 2; ++kt) {
    const int c = kt & 1;
    PH0(c, STAGE_OP(c ^ 1, 1, kt + 1));        // B(kt+1) -> dead buf
    PH1(c, STAGE_OP(c, 0, kt + 2), VM2(););    // A(kt+2) -> current buf
  }
  {
    const int c = (NT - 2) & 1;
    PH0(c, STAGE_OP(c ^ 1, 1, NT - 1));
    PH1(c, ;, VM0(););
  }
  {
    const int c = (NT - 1) & 1;
    PH0(c, ;);
    PH1(c, ;, ;);
  }

  // epilogue: C/D layout col=lane&15, row=(lane>>4)*4+reg
#pragma unroll
  for (int i = 0; i < 8; ++i) {
    int row0 = m0 + wm + i * 16 + (lane >> 4) * 4;
#pragma unroll
    for (int j = 0; j < 4; ++j) {
      int col = n0 + wn + j * 16 + (lane & 15);
      if (col < Nout) {
        float badd = bias ? bias[col] : 0.f;
#pragma unroll
        for (int r2 = 0; r2 < 4; ++r2)
          C[(size_t)(row0 + r2) * Nout + col] = acc[i][j][r2] + badd;
      }
    }
  }
}

// ---------------- E3: switch softmax + V ----------------
__global__ __launch_bounds__(256) void k_switch(
    const float* __restrict__ AH, const float* __restrict__ AG,
    const float* __restrict__ q, const float* __restrict__ wsw,
    const float* __restrict__ H, const float* __restrict__ G,
    unsigned short* __restrict__ Vbf, float* __restrict__ sw_out)
{
  int bl = blockIdx.x;
  int b = bl / LL;
  int tid = threadIdx.x;
  float aH = 0.f, aG = 0.f;
  for (int h = tid; h < HID; h += 256) {
    float qv = q[b * HID + h], w = wsw[h];
    aH += fast_tanh(AH[(size_t)bl * HID + h] + qv) * w;
    aG += fast_tanh(AG[(size_t)bl * HID + h] + qv) * w;
  }
#pragma unroll
  for (int off = 32; off > 0; off >>= 1) {
    aH += __shfl_down(aH, off);
    aG += __shfl_down(aG, off);
  }
  __shared__ float redH[4], redG[4];
  int lane = tid & 63, wave = tid >> 6;
  if (lane == 0) { redH[wave] = aH; redG[wave] = aG; }
  __syncthreads();
  float sH = redH[0] + redH[1] + redH[2] + redH[3];
  float sG = redG[0] + redG[1] + redG[2] + redG[3];
  float m = fmaxf(sH, sG);
  float e0 = __expf(sH - m), e1 = __expf(sG - m);
  float inv = 1.f / (e0 + e1);
  float sw0 = e0 * inv, sw1 = e1 * inv;
  if (tid == 0) { sw_out[bl * 2] = sw0; sw_out[bl * 2 + 1] = sw1; }
  for (int h = tid; h < HID; h += 256) {
    float v = sw0 * H[(size_t)bl * HID + h] + sw1 * G[(size_t)bl * HID + h];
    Vbf[(size_t)bl * HID + h] = f2bf(v);
  }
}

// ---------------- E4: z_t/z_s -> alpha/beta -> c_hat+hiddens ----------------
__global__ __launch_bounds__(256) void k_attn(
    const float* __restrict__ PV, const float* __restrict__ PG,
    const float* __restrict__ SS, const float* __restrict__ wh,
    const unsigned short* __restrict__ stbf, const unsigned short* __restrict__ Vbf,
    const float* __restrict__ hiddens,
    float* __restrict__ alpha_out, float* __restrict__ beta_out,
    unsigned short* __restrict__ chh)
{
  const int TG = 4;
  int b  = blockIdx.x / (TT / TG);
  int t0 = (blockIdx.x % (TT / TG)) * TG;
  int tid = threadIdx.x;
  __shared__ float pg_s[TG][LL], wh_s[LL], zz[TG][LL + 1], alpha_s[TG][LL], beta_sh[TG];

  if (tid < LL) wh_s[tid] = wh[tid];
  if (tid < TG * LL) {
    int tt = tid / LL, k = tid - tt * LL;
    pg_s[tt][k] = PG[(size_t)(b * TT + t0 + tt) * 64 + k];
  }
  __syncthreads();

  if (tid < TG * (LL + 1)) {
    int tt = tid / (LL + 1), l = tid - tt * (LL + 1);
    const float* src = (l < LL) ? &PV[((size_t)b * LL + l) * 64]
                                : &SS[(size_t)(b * TT + t0 + tt) * 64];
    float acc = 0.f;
    for (int k = 0; k < LL; ++k) acc += fast_tanh(src[k] + pg_s[tt][k]) * wh_s[k];
    zz[tt][l] = acc;
  }
  __syncthreads();

  if (tid < TG) {
    int tt = tid, bt = b * TT + t0 + tt;
    float mx = -1e30f;
    for (int l = 0; l < LL; ++l) mx = fmaxf(mx, zz[tt][l]);
    float sum = 0.f;
    for (int l = 0; l < LL; ++l) { float e = __expf(zz[tt][l] - mx); alpha_s[tt][l] = e; sum += e; }
    float inv = 1.f / sum;
    for (int l = 0; l < LL; ++l) {
      alpha_s[tt][l] *= inv;
      alpha_out[(size_t)bt * LL + l] = alpha_s[tt][l];
    }
    float mx2 = fmaxf(mx, zz[tt][LL]);
    float s2 = 0.f;
    for (int l = 0; l <= LL; ++l) s2 += __expf(zz[tt][l] - mx2);
    float bet = __expf(zz[tt][LL] - mx2) / s2;
    beta_sh[tt] = bet;
    beta_out[bt] = bet;
  }
  __syncthreads();

  for (int h = tid; h < HID; h += 256) {
    float ct[TG] = {0.f, 0.f, 0.f, 0.f};
    for (int l = 0; l < LL; ++l) {
      float v = bf2f(Vbf[((size_t)b * LL + l) * HID + h]);
#pragma unroll
      for (int tt = 0; tt < TG; ++tt) ct[tt] += alpha_s[tt][l] * v;
    }
#pragma unroll
    for (int tt = 0; tt < TG; ++tt) {
      int bt = b * TT + t0 + tt;
      float bet = beta_sh[tt];
      float s = bf2f(stbf[(size_t)bt * HID + h]);
      float chat = bet * s + (1.f - bet) * ct[tt];
      chh[(size_t)bt * HID + h] = f2bf(chat + hiddens[(size_t)bt * HID + h]);
    }
  }
}

// ---------------- launcher ----------------
extern "C" void kernel_launch(void* const* d_in, const int* in_sizes, int n_in,
                              void* d_out, int out_size, void* d_ws, size_t ws_size,
                              hipStream_t stream)
{
  const float* x       = (const float*)d_in[0];
  const float* hiddens = (const float*)d_in[1];
  const float* cells   = (const float*)d_in[2];
  const float* G       = (const float*)d_in[3];
  const float* H       = (const float*)d_in[4];
  const float* W_sx    = (const float*)d_in[5];
  const float* W_sh    = (const float*)d_in[6];
  const float* W_ax    = (const float*)d_in[7];
  const float* W_ah    = (const float*)d_in[8];
  const float* W_ag    = (const float*)d_in[9];
  const float* w_sw    = (const float*)d_in[10];
  const float* Wv      = (const float*)d_in[11];
  const float* Wg      = (const float*)d_in[12];
  const float* Ws      = (const float*)d_in[13];
  const float* wh      = (const float*)d_in[14];
  const float* W_mlp   = (const float*)d_in[15];
  const float* b_mlp   = (const float*)d_in[16];

  float* scores = (float*)d_out;
  float* alpha  = scores + (size_t)BT * VOC;
  float* beta   = alpha + (size_t)BT * LL;
  float* swout  = beta + BT;

  char* wsp = (char*)d_ws;
  size_t off = 0;
  auto alloc = [&](size_t bytes) -> char* {
    char* p = wsp + off;
    off += (bytes + 255) & ~(size_t)255;
    return p;
  };

  unsigned short* xh     = (unsigned short*)alloc((size_t)BT * K2 * 2);   // [x | hprev]
  unsigned short* wsxh   = (unsigned short*)alloc((size_t)HID * K2 * 2);  // [W_sx | W_sh]
  unsigned short* waxb   = (unsigned short*)alloc((size_t)HID * E2 * 2);
  unsigned short* wahb   = (unsigned short*)alloc((size_t)HID * HID * 2);
  unsigned short* wagb   = (unsigned short*)alloc((size_t)HID * HID * 2);
  unsigned short* Hbf    = (unsigned short*)alloc((size_t)BL * HID * 2);
  unsigned short* Gbf    = (unsigned short*)alloc((size_t)BL * HID * 2);
  unsigned short* hidbf  = (unsigned short*)alloc((size_t)BT * HID * 2);
  unsigned short* wvb    = (unsigned short*)alloc((size_t)NPAD_S * HID * 2);
  unsigned short* wgb    = (unsigned short*)alloc((size_t)NPAD_S * HID * 2);
  unsigned short* wsb    = (unsigned short*)alloc((size_t)NPAD_S * HID * 2);
  unsigned short* wmlpb  = (unsigned short*)alloc((size_t)NPAD_MLP * HID * 2);
  unsigned short* Vbf    = (unsigned short*)alloc((size_t)BL * HID * 2);
  unsigned short* stbf   = (unsigned short*)alloc((size_t)BT * HID * 2);
  unsigned short* chh    = (unsigned short*)alloc((size_t)BT * HID * 2);
  unsigned short* xmbf   = (unsigned short*)alloc((size_t)BB * E2 * 2);
  float* AH = (float*)alloc((size_t)BL * HID * 4);
  float* AG = (float*)alloc((size_t)BL * HID * 4);
  float* qb = (float*)alloc((size_t)BB * HID * 4);
  float* PV = (float*)alloc((size_t)BL * 64 * 4);
  float* PG = (float*)alloc((size_t)BT * 64 * 4);
  float* SS = (float*)alloc((size_t)BT * 64 * 4);
  (void)ws_size; (void)in_sizes; (void)n_in; (void)out_size;

  // --- 1: fused converts (strided-dst) ---
  SegTable tab;
  int blk = 0, si = 0;
  auto seg = [&](const float* s, unsigned short* d, int n4, int rl4, int dstride4,
                 int dcol4, int nrows, int mode) {
    tab.s[si].src = s; tab.s[si].dst = d; tab.s[si].n4 = n4; tab.s[si].rl4 = rl4;
    tab.s[si].dstride4 = dstride4; tab.s[si].dcol4 = dcol4;
    tab.s[si].nrows = nrows; tab.s[si].mode = mode; tab.s[si].blk0 = blk;
    blk += (n4 + CHUNK4 - 1) / CHUNK4; ++si;
  };
  seg(W_sx,    wsxh,  HID * 384, 384, 576, 0,   0, 0);
  seg(W_sh,    wsxh,  HID * 192, 192, 576, 384, 0, 0);
  seg(x,       xh,    BT * 384,  384, 576, 0,   0, 0);
  seg(hiddens, xh,    BT * 192,  192, 576, 384, 0, 2);   // shifted h_{t-1}
  seg(W_ax,    waxb,  HID * 384, 384, 384, 0,   0, 0);
  seg(W_ah,    wahb,  HID * 192, 192, 192, 0,   0, 0);
  seg(W_ag,    wagb,  HID * 192, 192, 192, 0,   0, 0);
  seg(H,       Hbf,   BL * 192,  192, 192, 0,   0, 0);
  seg(G,       Gbf,   BL * 192,  192, 192, 0,   0, 0);
  seg(hiddens, hidbf, BT * 192,  192, 192, 0,   0, 0);
  seg(Wv,      wvb,   NPAD_S * 192, 192, 192, 0, LL, 1);
  seg(Wg,      wgb,   NPAD_S * 192, 192, 192, 0, LL, 1);
  seg(Ws,      wsb,   NPAD_S * 192, 192, 192, 0, LL, 1);
  seg(W_mlp,   wmlpb, NPAD_MLP * 192, 192, 192, 0, VOC, 1);
  k_convall<<<blk, 256, 0, stream>>>(tab);

  // --- 2: x time-mean (for q) ---
  k_xmean<<<BB * 6, 256, 0, stream>>>(x, xmbf);

  // --- 3: mega GEMM on 128^2 2-phase (486 blocks): st(fused), ah, ag, q ---
  SSegTable mt;
  mt.s[0] = SSeg{xh,   wsxh, nullptr, nullptr, cells, stbf, BT, HID, K2,  30, 0,   1};
  mt.s[1] = SSeg{Hbf,  wahb, AH,      nullptr, nullptr, nullptr, BL, HID, HID, 25, 180, 0};
  mt.s[2] = SSeg{Gbf,  wagb, AG,      nullptr, nullptr, nullptr, BL, HID, HID, 25, 330, 0};
  mt.s[3] = SSeg{xmbf, waxb, qb,      nullptr, nullptr, nullptr, BB, HID, E2,  1,  480, 0};
  gemm_bt_seg<<<486, 256, 0, stream>>>(mt);

  // --- 4: switch ---
  k_switch<<<BL, 256, 0, stream>>>(AH, AG, qb, w_sw, H, G, Vbf, swout);

  // --- 5: skinny GEMMs (one segmented dispatch) ---
  SSegTable st;
  st.s[0] = SSeg{Vbf,   wvb, PV, nullptr, nullptr, nullptr, BL, 64, HID, 25, 0,  0};
  st.s[1] = SSeg{hidbf, wgb, PG, nullptr, nullptr, nullptr, BT, 64, HID, 30, 25, 0};
  st.s[2] = SSeg{stbf,  wsb, SS, nullptr, nullptr, nullptr, BT, 64, HID, 30, 55, 0};
  st.s[3] = st.s[2]; st.s[3].blk0 = 0x7fffffff;
  gemm_bt_seg<<<85, 256, 0, stream>>>(st);

  // --- 6: attention epilogue ---
  k_attn<<<BB * (TT / 4), 256, 0, stream>>>(PV, PG, SS, wh, stbf, Vbf, hiddens,
                                            alpha, beta, chh);

  // --- 7: scores GEMM (600 blocks, fp32+bias; M=3840=15x256 exact) ---
  gemm_sc<<<15 * 40, 512, 65536, stream>>>(chh, wmlpb, scores, b_mlp, BT, VOC, HID, 15);
}

// Round 12
// 304.694 us; speedup vs baseline: 4.9760x; 1.0675x over previous
//
#include <hip/hip_runtime.h>

#define BB 64
#define TT 60
#define LL 49
#define HID 768
#define E2 1536
#define K2 2304          // E2 + HID (concat for s_t GEMM)
#define VOC 10000
#define BT (BB*TT)      // 3840
#define BL (BB*LL)      // 3136
#define NPAD_MLP 10240
#define NPAD_S 128

typedef __bf16 bf16x8 __attribute__((ext_vector_type(8)));
typedef float f32x4 __attribute__((ext_vector_type(4)));

__device__ __forceinline__ unsigned short f2bf(float f) {
  union { float f; unsigned int u; } v; v.f = f;
  unsigned int u = v.u;
  return (unsigned short)((u + 0x7fffu + ((u >> 16) & 1u)) >> 16);  // RNE
}
__device__ __forceinline__ float bf2f(unsigned short h) {
  union { unsigned int u; float f; } v; v.u = ((unsigned int)h) << 16;
  return v.f;
}
__device__ __forceinline__ float fast_tanh(float x) {
  float e = __expf(2.f * x);
  return 1.f - 2.f / (e + 1.f);
}
__device__ __forceinline__ float fast_sigmoid(float x) {
  return 1.f / (1.f + __expf(-x));
}

// ---------------- fused convert with strided destination ----------------
#define NSEG 14
#define CHUNK4 2048
struct SegT {
  const float* src;
  unsigned short* dst;
  int n4;        // total vec4 elements (source-logical)
  int rl4;       // source row length in vec4
  int dstride4;  // dst row stride in vec4
  int dcol4;     // dst col offset in vec4
  int nrows;     // valid rows (mode 1)
  int mode;      // 0 plain, 1 pad-rows, 2 timestep-shift
  int blk0;
};
struct SegTable { SegT s[NSEG]; };

__global__ __launch_bounds__(256) void k_convall(SegTable tab) {
  int b = blockIdx.x;
  int si = 0;
#pragma unroll
  for (int i = 1; i < NSEG; ++i) si += (b >= tab.s[i].blk0);
  SegT sg = tab.s[si];
  int lb = b - sg.blk0;
  int end = (lb + 1) * CHUNK4; end = end < sg.n4 ? end : sg.n4;
  for (int i = lb * CHUNK4 + threadIdx.x; i < end; i += 256) {
    int row = i / sg.rl4, c = i - row * sg.rl4;
    ushort4 o; o.x = o.y = o.z = o.w = 0;
    if (sg.mode == 0) {
      float4 v = ((const float4*)sg.src)[i];
      o.x = f2bf(v.x); o.y = f2bf(v.y); o.z = f2bf(v.z); o.w = f2bf(v.w);
    } else if (sg.mode == 1) {
      if (row < sg.nrows) {
        float4 v = ((const float4*)sg.src)[i];
        o.x = f2bf(v.x); o.y = f2bf(v.y); o.z = f2bf(v.z); o.w = f2bf(v.w);
      }
    } else {  // timestep shift: row bt -> src row bt-1, zeros at t==0
      if (row % TT != 0) {
        float4 v = ((const float4*)sg.src)[i - sg.rl4];
        o.x = f2bf(v.x); o.y = f2bf(v.y); o.z = f2bf(v.z); o.w = f2bf(v.w);
      }
    }
    ((ushort4*)sg.dst)[(size_t)row * sg.dstride4 + sg.dcol4 + c] = o;
  }
}

// ---------------- k_xmean: xm[b,c] = bf16(mean_t x[b,t,c]) ----------------
__global__ __launch_bounds__(256) void k_xmean(const float* __restrict__ x,
                                               unsigned short* __restrict__ xm) {
  int b = blockIdx.x / 6;
  int c = (blockIdx.x % 6) * 256 + threadIdx.x;
  float s = 0.f;
  for (int t = 0; t < TT; ++t) s += x[((size_t)b * TT + t) * E2 + c];
  xm[(size_t)b * E2 + c] = f2bf(s * (1.f / 60.f));
}

// ---------------- segmented 128x64 2-phase GEMM (mega + skinny) ----------------
// Tile 128x64, BK=32, 4 waves (wave-tile 64x32, acc[4][2]=32 VGPR), LDS 12KB.
// Rationale (R11 post-mortem): mid GEMMs are parallelism-starved (N=768 ->
// only 180 blocks of 128^2, 0.85 blk/CU, staging latency fully exposed).
// 128x64 tiles double the grid (972 blocks, ~3.8/CU) -> cross-block overlap
// hides the 2-barrier K-step latency (m114/m97 regime needs >=3 blk/CU).
// Epilogue modes: 0 = fp32 (+bias); 1 = bf16 sigmoid(acc)*tanh(aux).
struct SSeg {
  const unsigned short* A; const unsigned short* B;
  float* C; const float* bias; const float* aux; unsigned short* outbf;
  int M, Nout, K, nMblk, blk0, emode;
};
#define NSSEG 4
struct SSegTable { SSeg s[NSSEG]; };

__global__ __launch_bounds__(256) void gemm_bt64_seg(SSegTable tab)
{
  __shared__ __attribute__((aligned(16))) unsigned short As[128*32];
  __shared__ __attribute__((aligned(16))) unsigned short Bs[64*32];
  const int tid  = threadIdx.x;
  const int lane = tid & 63;
  const int wave = tid >> 6;

  const int nwg = gridDim.x;
  const int id  = blockIdx.x;
  const int q = nwg >> 3, r = nwg & 7;
  const int xcd = id & 7, lo = id >> 3;
  const int wgid = (xcd < r ? xcd * (q + 1) : r * (q + 1) + (xcd - r) * q) + lo;

  int si = 0;
#pragma unroll
  for (int i = 1; i < NSSEG; ++i) si += (wgid >= tab.s[i].blk0);
  const SSeg sg = tab.s[si];
  const int lwg = wgid - sg.blk0;
  const int mb = lwg % sg.nMblk;
  const int nb = lwg / sg.nMblk;
  const int M = sg.M, Nout = sg.Nout, K = sg.K;
  const unsigned short* __restrict__ A  = sg.A;
  const unsigned short* __restrict__ Bw = sg.B;
  const int m0 = mb * 128;
  const int n0 = nb * 64;
  const int wm = (wave & 1) * 64;   // 0 or 64
  const int wn = (wave >> 1) * 32;  // 0 or 32

  f32x4 acc[4][2];
#pragma unroll
  for (int i = 0; i < 4; ++i)
#pragma unroll
    for (int j = 0; j < 2; ++j) acc[i][j] = f32x4{0.f, 0.f, 0.f, 0.f};

  const int lrow = lane & 15;
  const int kb   = (lane >> 4) * 8;

  for (int k0 = 0; k0 < K; k0 += 32) {
    __syncthreads();
    // A: 128 rows x 32 cols = 512 x 16B slots (2 lines); B: 64 rows = 256 slots (1 line)
#pragma unroll
    for (int p = 0; p < 2; ++p) {
      int slot = p * 256 + wave * 64 + lane;
      int row = slot >> 2, c8 = slot & 3;
      int ar = m0 + row; ar = ar < M ? ar : (M - 1);
      const unsigned short* asrc = A + (size_t)ar * K + k0 + c8 * 8;
      __builtin_amdgcn_global_load_lds(
          (const __attribute__((address_space(1))) void*)asrc,
          (__attribute__((address_space(3))) void*)&As[slot * 8],
          16, 0, 0);
    }
    {
      int slot = wave * 64 + lane;
      int row = slot >> 2, c8 = slot & 3;
      const unsigned short* bsrc = Bw + (size_t)(n0 + row) * K + k0 + c8 * 8;
      __builtin_amdgcn_global_load_lds(
          (const __attribute__((address_space(1))) void*)bsrc,
          (__attribute__((address_space(3))) void*)&Bs[slot * 8],
          16, 0, 0);
    }
    __syncthreads();

    bf16x8 av[4], bv[2];
#pragma unroll
    for (int i = 0; i < 4; ++i)
      av[i] = *(const bf16x8*)&As[(wm + i * 16 + lrow) * 32 + kb];
#pragma unroll
    for (int j = 0; j < 2; ++j)
      bv[j] = *(const bf16x8*)&Bs[(wn + j * 16 + lrow) * 32 + kb];
#pragma unroll
    for (int i = 0; i < 4; ++i)
#pragma unroll
      for (int j = 0; j < 2; ++j)
        acc[i][j] = __builtin_amdgcn_mfma_f32_16x16x32_bf16(av[i], bv[j], acc[i][j], 0, 0, 0);
  }

  const int cr = (lane >> 4) * 4;
  const int cc = lane & 15;
  if (sg.emode == 0) {
    float* __restrict__ C = sg.C;
    const float* __restrict__ bias = sg.bias;
#pragma unroll
    for (int i = 0; i < 4; ++i) {
      int row0 = m0 + wm + i * 16 + cr;
#pragma unroll
      for (int j = 0; j < 2; ++j) {
        int col = n0 + wn + j * 16 + cc;
        if (col < Nout) {
          float badd = bias ? bias[col] : 0.f;
#pragma unroll
          for (int r2 = 0; r2 < 4; ++r2) {
            int row = row0 + r2;
            if (row < M) C[(size_t)row * Nout + col] = acc[i][j][r2] + badd;
          }
        }
      }
    }
  } else {
    // s_t epilogue: bf16( sigmoid(acc) * tanh(cells) )
    const float* __restrict__ cells = sg.aux;
    unsigned short* __restrict__ ob = sg.outbf;
#pragma unroll
    for (int i = 0; i < 4; ++i) {
      int row0 = m0 + wm + i * 16 + cr;
#pragma unroll
      for (int j = 0; j < 2; ++j) {
        int col = n0 + wn + j * 16 + cc;
        if (col < Nout) {
#pragma unroll
          for (int r2 = 0; r2 < 4; ++r2) {
            int row = row0 + r2;
            if (row < M) {
              float cv = cells[(size_t)row * Nout + col];
              ob[(size_t)row * Nout + col] = f2bf(fast_sigmoid(acc[i][j][r2]) * fast_tanh(cv));
            }
          }
        }
      }
    }
  }
}

// ---------------- 256^2 lean pipelined GEMM (scores): BK=32, 2-buffer, 64KB ----------------
// launch_bounds(512,2): 128 arch-VGPR (acc in unified AGPR half, no spill —
// R10-verified); 64KB LDS x2 = 128KB -> 2 blocks/CU. Tile kt uses buf c=kt&1.
// PH0(kt) stages B(kt+1)->buf c^1 (dead); PH1(kt) stages A(kt+2)->buf c.
// VM2 at tile end (counted, never 0 mid-loop).
// Swizzle (both-sides, rule #21): 16B-slot s' = s ^ ((row>>1)&3).
#define BARR() do { asm volatile("" ::: "memory"); __builtin_amdgcn_s_barrier(); \
                    asm volatile("" ::: "memory"); } while (0)
#define VM2() asm volatile("s_waitcnt vmcnt(2)" ::: "memory")
#define VM0() asm volatile("s_waitcnt vmcnt(0)" ::: "memory")

#define STAGE_OP(bufi, op, kt) do {                                             \
  int k0_ = (kt) * 32;                                                          \
  _Pragma("unroll")                                                             \
  for (int l_ = 0; l_ < 2; ++l_) {                                              \
    int rr_ = l_ * 128 + sr0;                                                   \
    int ss_ = ssp ^ ((rr_ >> 1) & 3);                                           \
    int gr_ = (op) ? (n0 + rr_) : (m0 + rr_);                                   \
    const unsigned short* src_ = ((op) ? Bw : Ap) + (size_t)gr_ * K + k0_ + ss_ * 8; \
    char* dst_ = smem + (bufi) * 32768 + (op) * 16384 + l_ * 8192 + w * 1024;   \
    __builtin_amdgcn_global_load_lds(                                           \
        (const __attribute__((address_space(1))) void*)src_,                    \
        (__attribute__((address_space(3))) void*)dst_, 16, 0, 0);               \
  }                                                                             \
} while (0)

#define LDA(bufi, row) (*(const bf16x8*)(smem + (bufi) * 32768 + (row) * 64 + (cg ^ (((row) >> 1) & 3)) * 16))
#define LDB(bufi, row) (*(const bf16x8*)(smem + (bufi) * 32768 + 16384 + (row) * 64 + (cg ^ (((row) >> 1) & 3)) * 16))

#define PH0(bufi, STAGE_STMT) do {                                              \
  STAGE_STMT;                                                                   \
  bf16x8 bfr0 = LDB(bufi, wn + lrow);                                           \
  bf16x8 bfr1 = LDB(bufi, wn + 16 + lrow);                                      \
  _Pragma("unroll")                                                             \
  for (int i_ = 0; i_ < 8; ++i_) afr[i_] = LDA(bufi, wm + i_ * 16 + lrow);      \
  __builtin_amdgcn_s_setprio(1);                                                \
  _Pragma("unroll")                                                             \
  for (int i_ = 0; i_ < 8; ++i_) {                                              \
    acc[i_][0] = __builtin_amdgcn_mfma_f32_16x16x32_bf16(afr[i_], bfr0, acc[i_][0], 0, 0, 0); \
    acc[i_][1] = __builtin_amdgcn_mfma_f32_16x16x32_bf16(afr[i_], bfr1, acc[i_][1], 0, 0, 0); \
  }                                                                             \
  __builtin_amdgcn_s_setprio(0);                                                \
  BARR();                                                                       \
} while (0)

#define PH1(bufi, STAGE_STMT, VM_STMT) do {                                     \
  STAGE_STMT;                                                                   \
  bf16x8 bfr0 = LDB(bufi, wn + 32 + lrow);                                      \
  bf16x8 bfr1 = LDB(bufi, wn + 48 + lrow);                                      \
  __builtin_amdgcn_s_setprio(1);                                                \
  _Pragma("unroll")                                                             \
  for (int i_ = 0; i_ < 8; ++i_) {                                              \
    acc[i_][2] = __builtin_amdgcn_mfma_f32_16x16x32_bf16(afr[i_], bfr0, acc[i_][2], 0, 0, 0); \
    acc[i_][3] = __builtin_amdgcn_mfma_f32_16x16x32_bf16(afr[i_], bfr1, acc[i_][3], 0, 0, 0); \
  }                                                                             \
  __builtin_amdgcn_s_setprio(0);                                                \
  VM_STMT;                                                                      \
  BARR();                                                                       \
} while (0)

__global__ __launch_bounds__(512, 2) void gemm_sc(
    const unsigned short* __restrict__ Ap,
    const unsigned short* __restrict__ Bw,
    float* __restrict__ C,
    const float* __restrict__ bias,
    int M, int Nout, int K, int nMblk)
{
  extern __shared__ char smem[];
  const int tid  = threadIdx.x;
  const int lane = tid & 63;
  const int w    = tid >> 6;              // 0..7
  const int lrow = lane & 15;
  const int cg   = lane >> 4;             // logical 16B slot
  const int sr0  = w * 16 + (lane >> 2);  // stage row (l_=0)
  const int ssp  = lane & 3;              // physical 16B slot

  const int nwg = gridDim.x;
  const int id  = blockIdx.x;
  const int q = nwg >> 3, r = nwg & 7;
  const int xcd = id & 7, lo = id >> 3;
  const int wgid = (xcd < r ? xcd * (q + 1) : r * (q + 1) + (xcd - r) * q) + lo;
  const int mb = wgid % nMblk;
  const int nb = wgid / nMblk;

  const int m0 = mb * 256;
  const int n0 = nb * 256;
  const int wm = (w >> 2) * 128;   // 0 or 128
  const int wn = (w & 3) * 64;     // 0,64,128,192

  f32x4 acc[8][4];
#pragma unroll
  for (int i = 0; i < 8; ++i)
#pragma unroll
    for (int j = 0; j < 4; ++j) acc[i][j] = f32x4{0.f, 0.f, 0.f, 0.f};
  bf16x8 afr[8];

  const int NT = K >> 5;  // K/32, >= 3

  // prologue: A(0),B(0),A(1) = 6 loads; VM2 -> tile0's 4 arrived
  STAGE_OP(0, 0, 0);
  STAGE_OP(0, 1, 0);
  STAGE_OP(1, 0, 1);
  VM2();
  BARR();

  for (int kt = 0; kt < NT - 2; ++kt) {
    const int c = kt & 1;
    PH0(c, STAGE_OP(c ^ 1, 1, kt + 1));        // B(kt+1) -> dead buf
    PH1(c, STAGE_OP(c, 0, kt + 2), VM2(););    // A(kt+2) -> current buf
  }
  {
    const int c = (NT - 2) & 1;
    PH0(c, STAGE_OP(c ^ 1, 1, NT - 1));
    PH1(c, ;, VM0(););
  }
  {
    const int c = (NT - 1) & 1;
    PH0(c, ;);
    PH1(c, ;, ;);
  }

  // epilogue: C/D layout col=lane&15, row=(lane>>4)*4+reg
#pragma unroll
  for (int i = 0; i < 8; ++i) {
    int row0 = m0 + wm + i * 16 + (lane >> 4) * 4;
#pragma unroll
    for (int j = 0; j < 4; ++j) {
      int col = n0 + wn + j * 16 + (lane & 15);
      if (col < Nout) {
        float badd = bias ? bias[col] : 0.f;
#pragma unroll
        for (int r2 = 0; r2 < 4; ++r2)
          C[(size_t)(row0 + r2) * Nout + col] = acc[i][j][r2] + badd;
      }
    }
  }
}

// ---------------- E3: switch softmax + V ----------------
__global__ __launch_bounds__(256) void k_switch(
    const float* __restrict__ AH, const float* __restrict__ AG,
    const float* __restrict__ q, const float* __restrict__ wsw,
    const float* __restrict__ H, const float* __restrict__ G,
    unsigned short* __restrict__ Vbf, float* __restrict__ sw_out)
{
  int bl = blockIdx.x;
  int b = bl / LL;
  int tid = threadIdx.x;
  float aH = 0.f, aG = 0.f;
  for (int h = tid; h < HID; h += 256) {
    float qv = q[b * HID + h], w = wsw[h];
    aH += fast_tanh(AH[(size_t)bl * HID + h] + qv) * w;
    aG += fast_tanh(AG[(size_t)bl * HID + h] + qv) * w;
  }
#pragma unroll
  for (int off = 32; off > 0; off >>= 1) {
    aH += __shfl_down(aH, off);
    aG += __shfl_down(aG, off);
  }
  __shared__ float redH[4], redG[4];
  int lane = tid & 63, wave = tid >> 6;
  if (lane == 0) { redH[wave] = aH; redG[wave] = aG; }
  __syncthreads();
  float sH = redH[0] + redH[1] + redH[2] + redH[3];
  float sG = redG[0] + redG[1] + redG[2] + redG[3];
  float m = fmaxf(sH, sG);
  float e0 = __expf(sH - m), e1 = __expf(sG - m);
  float inv = 1.f / (e0 + e1);
  float sw0 = e0 * inv, sw1 = e1 * inv;
  if (tid == 0) { sw_out[bl * 2] = sw0; sw_out[bl * 2 + 1] = sw1; }
  for (int h = tid; h < HID; h += 256) {
    float v = sw0 * H[(size_t)bl * HID + h] + sw1 * G[(size_t)bl * HID + h];
    Vbf[(size_t)bl * HID + h] = f2bf(v);
  }
}

// ---------------- E4: z_t/z_s -> alpha/beta -> c_hat+hiddens ----------------
__global__ __launch_bounds__(256) void k_attn(
    const float* __restrict__ PV, const float* __restrict__ PG,
    const float* __restrict__ SS, const float* __restrict__ wh,
    const unsigned short* __restrict__ stbf, const unsigned short* __restrict__ Vbf,
    const float* __restrict__ hiddens,
    float* __restrict__ alpha_out, float* __restrict__ beta_out,
    unsigned short* __restrict__ chh)
{
  const int TG = 4;
  int b  = blockIdx.x / (TT / TG);
  int t0 = (blockIdx.x % (TT / TG)) * TG;
  int tid = threadIdx.x;
  __shared__ float pg_s[TG][LL], wh_s[LL], zz[TG][LL + 1], alpha_s[TG][LL], beta_sh[TG];

  if (tid < LL) wh_s[tid] = wh[tid];
  if (tid < TG * LL) {
    int tt = tid / LL, k = tid - tt * LL;
    pg_s[tt][k] = PG[(size_t)(b * TT + t0 + tt) * 64 + k];
  }
  __syncthreads();

  if (tid < TG * (LL + 1)) {
    int tt = tid / (LL + 1), l = tid - tt * (LL + 1);
    const float* src = (l < LL) ? &PV[((size_t)b * LL + l) * 64]
                                : &SS[(size_t)(b * TT + t0 + tt) * 64];
    float acc = 0.f;
    for (int k = 0; k < LL; ++k) acc += fast_tanh(src[k] + pg_s[tt][k]) * wh_s[k];
    zz[tt][l] = acc;
  }
  __syncthreads();

  if (tid < TG) {
    int tt = tid, bt = b * TT + t0 + tt;
    float mx = -1e30f;
    for (int l = 0; l < LL; ++l) mx = fmaxf(mx, zz[tt][l]);
    float sum = 0.f;
    for (int l = 0; l < LL; ++l) { float e = __expf(zz[tt][l] - mx); alpha_s[tt][l] = e; sum += e; }
    float inv = 1.f / sum;
    for (int l = 0; l < LL; ++l) {
      alpha_s[tt][l] *= inv;
      alpha_out[(size_t)bt * LL + l] = alpha_s[tt][l];
    }
    float mx2 = fmaxf(mx, zz[tt][LL]);
    float s2 = 0.f;
    for (int l = 0; l <= LL; ++l) s2 += __expf(zz[tt][l] - mx2);
    float bet = __expf(zz[tt][LL] - mx2) / s2;
    beta_sh[tt] = bet;
    beta_out[bt] = bet;
  }
  __syncthreads();

  for (int h = tid; h < HID; h += 256) {
    float ct[TG] = {0.f, 0.f, 0.f, 0.f};
    for (int l = 0; l < LL; ++l) {
      float v = bf2f(Vbf[((size_t)b * LL + l) * HID + h]);
#pragma unroll
      for (int tt = 0; tt < TG; ++tt) ct[tt] += alpha_s[tt][l] * v;
    }
#pragma unroll
    for (int tt = 0; tt < TG; ++tt) {
      int bt = b * TT + t0 + tt;
      float bet = beta_sh[tt];
      float s = bf2f(stbf[(size_t)bt * HID + h]);
      float chat = bet * s + (1.f - bet) * ct[tt];
      chh[(size_t)bt * HID + h] = f2bf(chat + hiddens[(size_t)bt * HID + h]);
    }
  }
}

// ---------------- launcher ----------------
extern "C" void kernel_launch(void* const* d_in, const int* in_sizes, int n_in,
                              void* d_out, int out_size, void* d_ws, size_t ws_size,
                              hipStream_t stream)
{
  const float* x       = (const float*)d_in[0];
  const float* hiddens = (const float*)d_in[1];
  const float* cells   = (const float*)d_in[2];
  const float* G       = (const float*)d_in[3];
  const float* H       = (const float*)d_in[4];
  const float* W_sx    = (const float*)d_in[5];
  const float* W_sh    = (const float*)d_in[6];
  const float* W_ax    = (const float*)d_in[7];
  const float* W_ah    = (const float*)d_in[8];
  const float* W_ag    = (const float*)d_in[9];
  const float* w_sw    = (const float*)d_in[10];
  const float* Wv      = (const float*)d_in[11];
  const float* Wg      = (const float*)d_in[12];
  const float* Ws      = (const float*)d_in[13];
  const float* wh      = (const float*)d_in[14];
  const float* W_mlp   = (const float*)d_in[15];
  const float* b_mlp   = (const float*)d_in[16];

  float* scores = (float*)d_out;
  float* alpha  = scores + (size_t)BT * VOC;
  float* beta   = alpha + (size_t)BT * LL;
  float* swout  = beta + BT;

  char* wsp = (char*)d_ws;
  size_t off = 0;
  auto alloc = [&](size_t bytes) -> char* {
    char* p = wsp + off;
    off += (bytes + 255) & ~(size_t)255;
    return p;
  };

  unsigned short* xh     = (unsigned short*)alloc((size_t)BT * K2 * 2);   // [x | hprev]
  unsigned short* wsxh   = (unsigned short*)alloc((size_t)HID * K2 * 2);  // [W_sx | W_sh]
  unsigned short* waxb   = (unsigned short*)alloc((size_t)HID * E2 * 2);
  unsigned short* wahb   = (unsigned short*)alloc((size_t)HID * HID * 2);
  unsigned short* wagb   = (unsigned short*)alloc((size_t)HID * HID * 2);
  unsigned short* Hbf    = (unsigned short*)alloc((size_t)BL * HID * 2);
  unsigned short* Gbf    = (unsigned short*)alloc((size_t)BL * HID * 2);
  unsigned short* hidbf  = (unsigned short*)alloc((size_t)BT * HID * 2);
  unsigned short* wvb    = (unsigned short*)alloc((size_t)NPAD_S * HID * 2);
  unsigned short* wgb    = (unsigned short*)alloc((size_t)NPAD_S * HID * 2);
  unsigned short* wsb    = (unsigned short*)alloc((size_t)NPAD_S * HID * 2);
  unsigned short* wmlpb  = (unsigned short*)alloc((size_t)NPAD_MLP * HID * 2);
  unsigned short* Vbf    = (unsigned short*)alloc((size_t)BL * HID * 2);
  unsigned short* stbf   = (unsigned short*)alloc((size_t)BT * HID * 2);
  unsigned short* chh    = (unsigned short*)alloc((size_t)BT * HID * 2);
  unsigned short* xmbf   = (unsigned short*)alloc((size_t)BB * E2 * 2);
  float* AH = (float*)alloc((size_t)BL * HID * 4);
  float* AG = (float*)alloc((size_t)BL * HID * 4);
  float* qb = (float*)alloc((size_t)BB * HID * 4);
  float* PV = (float*)alloc((size_t)BL * 64 * 4);
  float* PG = (float*)alloc((size_t)BT * 64 * 4);
  float* SS = (float*)alloc((size_t)BT * 64 * 4);
  (void)ws_size; (void)in_sizes; (void)n_in; (void)out_size;

  // --- 1: fused converts (strided-dst) ---
  SegTable tab;
  int blk = 0, si = 0;
  auto seg = [&](const float* s, unsigned short* d, int n4, int rl4, int dstride4,
                 int dcol4, int nrows, int mode) {
    tab.s[si].src = s; tab.s[si].dst = d; tab.s[si].n4 = n4; tab.s[si].rl4 = rl4;
    tab.s[si].dstride4 = dstride4; tab.s[si].dcol4 = dcol4;
    tab.s[si].nrows = nrows; tab.s[si].mode = mode; tab.s[si].blk0 = blk;
    blk += (n4 + CHUNK4 - 1) / CHUNK4; ++si;
  };
  seg(W_sx,    wsxh,  HID * 384, 384, 576, 0,   0, 0);
  seg(W_sh,    wsxh,  HID * 192, 192, 576, 384, 0, 0);
  seg(x,       xh,    BT * 384,  384, 576, 0,   0, 0);
  seg(hiddens, xh,    BT * 192,  192, 576, 384, 0, 2);   // shifted h_{t-1}
  seg(W_ax,    waxb,  HID * 384, 384, 384, 0,   0, 0);
  seg(W_ah,    wahb,  HID * 192, 192, 192, 0,   0, 0);
  seg(W_ag,    wagb,  HID * 192, 192, 192, 0,   0, 0);
  seg(H,       Hbf,   BL * 192,  192, 192, 0,   0, 0);
  seg(G,       Gbf,   BL * 192,  192, 192, 0,   0, 0);
  seg(hiddens, hidbf, BT * 192,  192, 192, 0,   0, 0);
  seg(Wv,      wvb,   NPAD_S * 192, 192, 192, 0, LL, 1);
  seg(Wg,      wgb,   NPAD_S * 192, 192, 192, 0, LL, 1);
  seg(Ws,      wsb,   NPAD_S * 192, 192, 192, 0, LL, 1);
  seg(W_mlp,   wmlpb, NPAD_MLP * 192, 192, 192, 0, VOC, 1);
  k_convall<<<blk, 256, 0, stream>>>(tab);

  // --- 2: x time-mean (for q) ---
  k_xmean<<<BB * 6, 256, 0, stream>>>(x, xmbf);

  // --- 3: mega GEMM on 128x64 2-phase (972 blocks): st(fused), ah, ag, q ---
  SSegTable mt;
  mt.s[0] = SSeg{xh,   wsxh, nullptr, nullptr, cells, stbf, BT, HID, K2,  30, 0,   1};
  mt.s[1] = SSeg{Hbf,  wahb, AH,      nullptr, nullptr, nullptr, BL, HID, HID, 25, 360, 0};
  mt.s[2] = SSeg{Gbf,  wagb, AG,      nullptr, nullptr, nullptr, BL, HID, HID, 25, 660, 0};
  mt.s[3] = SSeg{xmbf, waxb, qb,      nullptr, nullptr, nullptr, BB, HID, E2,  1,  960, 0};
  gemm_bt64_seg<<<972, 256, 0, stream>>>(mt);

  // --- 4: switch ---
  k_switch<<<BL, 256, 0, stream>>>(AH, AG, qb, w_sw, H, G, Vbf, swout);

  // --- 5: skinny GEMMs (one segmented dispatch, N=64 -> 1 tile each) ---
  SSegTable st;
  st.s[0] = SSeg{Vbf,   wvb, PV, nullptr, nullptr, nullptr, BL, 64, HID, 25, 0,  0};
  st.s[1] = SSeg{hidbf, wgb, PG, nullptr, nullptr, nullptr, BT, 64, HID, 30, 25, 0};
  st.s[2] = SSeg{stbf,  wsb, SS, nullptr, nullptr, nullptr, BT, 64, HID, 30, 55, 0};
  st.s[3] = st.s[2]; st.s[3].blk0 = 0x7fffffff;
  gemm_bt64_seg<<<85, 256, 0, stream>>>(st);

  // --- 6: attention epilogue ---
  k_attn<<<BB * (TT / 4), 256, 0, stream>>>(PV, PG, SS, wh, stbf, Vbf, hiddens,
                                            alpha, beta, chh);

  // --- 7: scores GEMM (600 blocks, fp32+bias; M=3840=15x256 exact) ---
  gemm_sc<<<15 * 40, 512, 65536, stream>>>(chh, wmlpb, scores, b_mlp, BT, VOC, HID, 15);
}

// Round 13
// 300.808 us; speedup vs baseline: 5.0403x; 1.0129x over previous
//
#include <hip/hip_runtime.h>

#define BB 64
#define TT 60
#define LL 49
#define HID 768
#define E2 1536
#define K2 2304          // E2 + HID (concat for s_t GEMM)
#define VOC 10000
#define BT (BB*TT)      // 3840
#define BL (BB*LL)      // 3136
#define NPAD_MLP 10240
#define NPAD_S 128

typedef __bf16 bf16x8 __attribute__((ext_vector_type(8)));
typedef float f32x4 __attribute__((ext_vector_type(4)));

__device__ __forceinline__ unsigned short f2bf(float f) {
  union { float f; unsigned int u; } v; v.f = f;
  unsigned int u = v.u;
  return (unsigned short)((u + 0x7fffu + ((u >> 16) & 1u)) >> 16);  // RNE
}
__device__ __forceinline__ float bf2f(unsigned short h) {
  union { unsigned int u; float f; } v; v.u = ((unsigned int)h) << 16;
  return v.f;
}
__device__ __forceinline__ float fast_tanh(float x) {
  float e = __expf(2.f * x);
  return 1.f - 2.f / (e + 1.f);
}
__device__ __forceinline__ float fast_sigmoid(float x) {
  return 1.f / (1.f + __expf(-x));
}

// ---------------- fused convert with strided destination ----------------
#define NSEG 14
#define CHUNK4 2048
struct SegT {
  const float* src;
  unsigned short* dst;
  int n4, rl4, dstride4, dcol4, nrows, mode, blk0;
};
struct SegTable { SegT s[NSEG]; };

__global__ __launch_bounds__(256) void k_convall(SegTable tab) {
  int b = blockIdx.x;
  int si = 0;
#pragma unroll
  for (int i = 1; i < NSEG; ++i) si += (b >= tab.s[i].blk0);
  SegT sg = tab.s[si];
  int lb = b - sg.blk0;
  int end = (lb + 1) * CHUNK4; end = end < sg.n4 ? end : sg.n4;
  for (int i = lb * CHUNK4 + threadIdx.x; i < end; i += 256) {
    int row = i / sg.rl4, c = i - row * sg.rl4;
    ushort4 o; o.x = o.y = o.z = o.w = 0;
    if (sg.mode == 0) {
      float4 v = ((const float4*)sg.src)[i];
      o.x = f2bf(v.x); o.y = f2bf(v.y); o.z = f2bf(v.z); o.w = f2bf(v.w);
    } else if (sg.mode == 1) {
      if (row < sg.nrows) {
        float4 v = ((const float4*)sg.src)[i];
        o.x = f2bf(v.x); o.y = f2bf(v.y); o.z = f2bf(v.z); o.w = f2bf(v.w);
      }
    } else {
      if (row % TT != 0) {
        float4 v = ((const float4*)sg.src)[i - sg.rl4];
        o.x = f2bf(v.x); o.y = f2bf(v.y); o.z = f2bf(v.z); o.w = f2bf(v.w);
      }
    }
    ((ushort4*)sg.dst)[(size_t)row * sg.dstride4 + sg.dcol4 + c] = o;
  }
}

// ---------------- k_xmean ----------------
__global__ __launch_bounds__(256) void k_xmean(const float* __restrict__ x,
                                               unsigned short* __restrict__ xm) {
  int b = blockIdx.x / 6;
  int c = (blockIdx.x % 6) * 256 + threadIdx.x;
  float s = 0.f;
  for (int t = 0; t < TT; ++t) s += x[((size_t)b * TT + t) * E2 + c];
  xm[(size_t)b * E2 + c] = f2bf(s * (1.f / 60.f));
}

// ---------------- segmented 128x64 2-phase GEMM (mega + skinny) ----------------
// emode: 0 = fp32 C (+bias); 1 = bf16 sigmoid(acc)*tanh(aux); 2 = bf16 plain.
struct SSeg {
  const unsigned short* A; const unsigned short* B;
  float* C; const float* bias; const float* aux; unsigned short* outbf;
  int M, Nout, K, nMblk, blk0, emode;
};
#define NSSEG 4
struct SSegTable { SSeg s[NSSEG]; };

__global__ __launch_bounds__(256) void gemm_bt64_seg(SSegTable tab)
{
  __shared__ __attribute__((aligned(16))) unsigned short As[128*32];
  __shared__ __attribute__((aligned(16))) unsigned short Bs[64*32];
  const int tid  = threadIdx.x;
  const int lane = tid & 63;
  const int wave = tid >> 6;

  const int nwg = gridDim.x;
  const int id  = blockIdx.x;
  const int q = nwg >> 3, r = nwg & 7;
  const int xcd = id & 7, lo = id >> 3;
  const int wgid = (xcd < r ? xcd * (q + 1) : r * (q + 1) + (xcd - r) * q) + lo;

  int si = 0;
#pragma unroll
  for (int i = 1; i < NSSEG; ++i) si += (wgid >= tab.s[i].blk0);
  const SSeg sg = tab.s[si];
  const int lwg = wgid - sg.blk0;
  const int mb = lwg % sg.nMblk;
  const int nb = lwg / sg.nMblk;
  const int M = sg.M, Nout = sg.Nout, K = sg.K;
  const unsigned short* __restrict__ A  = sg.A;
  const unsigned short* __restrict__ Bw = sg.B;
  const int m0 = mb * 128;
  const int n0 = nb * 64;
  const int wm = (wave & 1) * 64;
  const int wn = (wave >> 1) * 32;

  f32x4 acc[4][2];
#pragma unroll
  for (int i = 0; i < 4; ++i)
#pragma unroll
    for (int j = 0; j < 2; ++j) acc[i][j] = f32x4{0.f, 0.f, 0.f, 0.f};

  const int lrow = lane & 15;
  const int kb   = (lane >> 4) * 8;

  for (int k0 = 0; k0 < K; k0 += 32) {
    __syncthreads();
#pragma unroll
    for (int p = 0; p < 2; ++p) {
      int slot = p * 256 + wave * 64 + lane;
      int row = slot >> 2, c8 = slot & 3;
      int ar = m0 + row; ar = ar < M ? ar : (M - 1);
      const unsigned short* asrc = A + (size_t)ar * K + k0 + c8 * 8;
      __builtin_amdgcn_global_load_lds(
          (const __attribute__((address_space(1))) void*)asrc,
          (__attribute__((address_space(3))) void*)&As[slot * 8],
          16, 0, 0);
    }
    {
      int slot = wave * 64 + lane;
      int row = slot >> 2, c8 = slot & 3;
      const unsigned short* bsrc = Bw + (size_t)(n0 + row) * K + k0 + c8 * 8;
      __builtin_amdgcn_global_load_lds(
          (const __attribute__((address_space(1))) void*)bsrc,
          (__attribute__((address_space(3))) void*)&Bs[slot * 8],
          16, 0, 0);
    }
    __syncthreads();

    bf16x8 av[4], bv[2];
#pragma unroll
    for (int i = 0; i < 4; ++i)
      av[i] = *(const bf16x8*)&As[(wm + i * 16 + lrow) * 32 + kb];
#pragma unroll
    for (int j = 0; j < 2; ++j)
      bv[j] = *(const bf16x8*)&Bs[(wn + j * 16 + lrow) * 32 + kb];
#pragma unroll
    for (int i = 0; i < 4; ++i)
#pragma unroll
      for (int j = 0; j < 2; ++j)
        acc[i][j] = __builtin_amdgcn_mfma_f32_16x16x32_bf16(av[i], bv[j], acc[i][j], 0, 0, 0);
  }

  const int cr = (lane >> 4) * 4;
  const int cc = lane & 15;
  if (sg.emode == 0) {
    float* __restrict__ C = sg.C;
    const float* __restrict__ bias = sg.bias;
#pragma unroll
    for (int i = 0; i < 4; ++i) {
      int row0 = m0 + wm + i * 16 + cr;
#pragma unroll
      for (int j = 0; j < 2; ++j) {
        int col = n0 + wn + j * 16 + cc;
        if (col < Nout) {
          float badd = bias ? bias[col] : 0.f;
#pragma unroll
          for (int r2 = 0; r2 < 4; ++r2) {
            int row = row0 + r2;
            if (row < M) C[(size_t)row * Nout + col] = acc[i][j][r2] + badd;
          }
        }
      }
    }
  } else if (sg.emode == 1) {
    const float* __restrict__ cells = sg.aux;
    unsigned short* __restrict__ ob = sg.outbf;
#pragma unroll
    for (int i = 0; i < 4; ++i) {
      int row0 = m0 + wm + i * 16 + cr;
#pragma unroll
      for (int j = 0; j < 2; ++j) {
        int col = n0 + wn + j * 16 + cc;
        if (col < Nout) {
#pragma unroll
          for (int r2 = 0; r2 < 4; ++r2) {
            int row = row0 + r2;
            if (row < M) {
              float cv = cells[(size_t)row * Nout + col];
              ob[(size_t)row * Nout + col] = f2bf(fast_sigmoid(acc[i][j][r2]) * fast_tanh(cv));
            }
          }
        }
      }
    }
  } else {
    unsigned short* __restrict__ ob = sg.outbf;
#pragma unroll
    for (int i = 0; i < 4; ++i) {
      int row0 = m0 + wm + i * 16 + cr;
#pragma unroll
      for (int j = 0; j < 2; ++j) {
        int col = n0 + wn + j * 16 + cc;
        if (col < Nout) {
#pragma unroll
          for (int r2 = 0; r2 < 4; ++r2) {
            int row = row0 + r2;
            if (row < M) ob[(size_t)row * Nout + col] = f2bf(acc[i][j][r2]);
          }
        }
      }
    }
  }
}

// ---------------- scores GEMM: 128x256 tile, 4 waves, wave-tile 64x128 ----------------
// Registers: acc[4][8]=128 + frags/addr ~70 -> ~200 <= 256 @ (256,2) => 2 blocks/CU
// of 4 waves (8 waves/SIMD-pair) -- cross-block overlap of barriers/epilogue.
// 42.7 FLOP/LDS-byte (per wave per K-tile: 12 b128 reads, 32 MFMA).
// LDS: 3 bufs x (A 8KB + B 16KB) = 72KB; x2 blocks = 144 <= 160.
// 3-buffer pipeline: tile kt uses buf kt%3; stage kt+2 during kt (panel dead
// since barrier closing kt-1); VM6 at tile end provably drains kt+1's 6 loads.
// Swizzle (both-sides, rule #21): 16B-slot s' = s ^ ((row>>1)&3).
#define VM6() asm volatile("s_waitcnt vmcnt(6)" ::: "memory")
#define VM0() asm volatile("s_waitcnt vmcnt(0)" ::: "memory")
#define BARR() do { asm volatile("" ::: "memory"); __builtin_amdgcn_s_barrier(); \
                    asm volatile("" ::: "memory"); } while (0)

// stage one K-tile (A: 2 units of 64 rows, B: 4 units of 64 rows); 6 loads/wave
#define SC_STAGE(bufi, kt) do {                                                 \
  int k0_ = (kt) * 32;                                                          \
  _Pragma("unroll")                                                             \
  for (int l_ = 0; l_ < 2; ++l_) {                                              \
    int rr_ = l_ * 64 + wave * 16 + (lane >> 2);                                \
    int ss_ = (lane & 3) ^ ((rr_ >> 1) & 3);                                    \
    const unsigned short* src_ = Ap + (size_t)(m0 + rr_) * K + k0_ + ss_ * 8;   \
    char* dst_ = smem + (bufi) * 24576 + l_ * 4096 + wave * 1024;               \
    __builtin_amdgcn_global_load_lds(                                           \
        (const __attribute__((address_space(1))) void*)src_,                    \
        (__attribute__((address_space(3))) void*)dst_, 16, 0, 0);               \
  }                                                                             \
  _Pragma("unroll")                                                             \
  for (int l_ = 0; l_ < 4; ++l_) {                                              \
    int rr_ = l_ * 64 + wave * 16 + (lane >> 2);                                \
    int ss_ = (lane & 3) ^ ((rr_ >> 1) & 3);                                    \
    const unsigned short* src_ = Bw + (size_t)(n0 + rr_) * K + k0_ + ss_ * 8;   \
    char* dst_ = smem + (bufi) * 24576 + 8192 + l_ * 4096 + wave * 1024;        \
    __builtin_amdgcn_global_load_lds(                                           \
        (const __attribute__((address_space(1))) void*)src_,                    \
        (__attribute__((address_space(3))) void*)dst_, 16, 0, 0);               \
  }                                                                             \
} while (0)

#define SC_LDA(bufi, row) (*(const bf16x8*)(smem + (bufi) * 24576 + (row) * 64 + ((cg ^ (((row) >> 1) & 3)) * 16)))
#define SC_LDB(bufi, row) (*(const bf16x8*)(smem + (bufi) * 24576 + 8192 + (row) * 64 + ((cg ^ (((row) >> 1) & 3)) * 16)))

#define SC_TILE(bufi, STAGE_STMT, VM_STMT) do {                                 \
  STAGE_STMT;                                                                   \
  bf16x8 afr0 = SC_LDA(bufi, wm + lrow);                                        \
  bf16x8 afr1 = SC_LDA(bufi, wm + 16 + lrow);                                   \
  bf16x8 afr2 = SC_LDA(bufi, wm + 32 + lrow);                                   \
  bf16x8 afr3 = SC_LDA(bufi, wm + 48 + lrow);                                   \
  __builtin_amdgcn_s_setprio(1);                                                \
  _Pragma("unroll")                                                             \
  for (int j_ = 0; j_ < 8; ++j_) {                                              \
    bf16x8 b_ = SC_LDB(bufi, wn + j_ * 16 + lrow);                              \
    acc[0][j_] = __builtin_amdgcn_mfma_f32_16x16x32_bf16(afr0, b_, acc[0][j_], 0, 0, 0); \
    acc[1][j_] = __builtin_amdgcn_mfma_f32_16x16x32_bf16(afr1, b_, acc[1][j_], 0, 0, 0); \
    acc[2][j_] = __builtin_amdgcn_mfma_f32_16x16x32_bf16(afr2, b_, acc[2][j_], 0, 0, 0); \
    acc[3][j_] = __builtin_amdgcn_mfma_f32_16x16x32_bf16(afr3, b_, acc[3][j_], 0, 0, 0); \
  }                                                                             \
  __builtin_amdgcn_s_setprio(0);                                                \
  VM_STMT;                                                                      \
  BARR();                                                                       \
} while (0)

__global__ __launch_bounds__(256, 2) void gemm_sc2(
    const unsigned short* __restrict__ Ap,
    const unsigned short* __restrict__ Bw,
    float* __restrict__ C,
    const float* __restrict__ bias,
    int M, int Nout, int K, int nMblk)
{
  extern __shared__ char smem[];
  const int tid  = threadIdx.x;
  const int lane = tid & 63;
  const int wave = tid >> 6;       // 0..3
  const int lrow = lane & 15;
  const int cg   = lane >> 4;

  const int nwg = gridDim.x;
  const int id  = blockIdx.x;
  const int q = nwg >> 3, r = nwg & 7;
  const int xcd = id & 7, lo = id >> 3;
  const int wgid = (xcd < r ? xcd * (q + 1) : r * (q + 1) + (xcd - r) * q) + lo;
  const int mb = wgid % nMblk;
  const int nb = wgid / nMblk;

  const int m0 = mb * 128;
  const int n0 = nb * 256;
  const int wm = (wave >> 1) * 64;   // 0 or 64
  const int wn = (wave & 1) * 128;   // 0 or 128

  f32x4 acc[4][8];
#pragma unroll
  for (int i = 0; i < 4; ++i)
#pragma unroll
    for (int j = 0; j < 8; ++j) acc[i][j] = f32x4{0.f, 0.f, 0.f, 0.f};

  const int NT = K >> 5;  // 24

  // prologue: stage tiles 0,1 (12 loads); VM6 -> tile0's 6 arrived
  SC_STAGE(0, 0);
  SC_STAGE(1, 1);
  VM6();
  BARR();

  int b = 0;
  for (int kt = 0; kt < NT - 2; ++kt) {
    int b2 = b + 2; if (b2 >= 3) b2 -= 3;
    SC_TILE(b, SC_STAGE(b2, kt + 2), VM6(););
    ++b; if (b == 3) b = 0;
  }
  SC_TILE(b, ;, VM0(););
  ++b; if (b == 3) b = 0;
  SC_TILE(b, ;, ;);

  // epilogue: C/D layout col=lane&15, row=(lane>>4)*4+reg; M multiple of 128
#pragma unroll
  for (int i = 0; i < 4; ++i) {
    int row0 = m0 + wm + i * 16 + (lane >> 4) * 4;
#pragma unroll
    for (int j = 0; j < 8; ++j) {
      int col = n0 + wn + j * 16 + (lane & 15);
      if (col < Nout) {
        float badd = bias ? bias[col] : 0.f;
#pragma unroll
        for (int r2 = 0; r2 < 4; ++r2)
          C[(size_t)(row0 + r2) * Nout + col] = acc[i][j][r2] + badd;
      }
    }
  }
}

// ---------------- E3: switch softmax + V (AH/AG in bf16) ----------------
__global__ __launch_bounds__(256) void k_switch(
    const unsigned short* __restrict__ AH, const unsigned short* __restrict__ AG,
    const float* __restrict__ q, const float* __restrict__ wsw,
    const float* __restrict__ H, const float* __restrict__ G,
    unsigned short* __restrict__ Vbf, float* __restrict__ sw_out)
{
  int bl = blockIdx.x;
  int b = bl / LL;
  int tid = threadIdx.x;
  float aH = 0.f, aG = 0.f;
  for (int h = tid; h < HID; h += 256) {
    float qv = q[b * HID + h], w = wsw[h];
    aH += fast_tanh(bf2f(AH[(size_t)bl * HID + h]) + qv) * w;
    aG += fast_tanh(bf2f(AG[(size_t)bl * HID + h]) + qv) * w;
  }
#pragma unroll
  for (int off = 32; off > 0; off >>= 1) {
    aH += __shfl_down(aH, off);
    aG += __shfl_down(aG, off);
  }
  __shared__ float redH[4], redG[4];
  int lane = tid & 63, wave = tid >> 6;
  if (lane == 0) { redH[wave] = aH; redG[wave] = aG; }
  __syncthreads();
  float sH = redH[0] + redH[1] + redH[2] + redH[3];
  float sG = redG[0] + redG[1] + redG[2] + redG[3];
  float m = fmaxf(sH, sG);
  float e0 = __expf(sH - m), e1 = __expf(sG - m);
  float inv = 1.f / (e0 + e1);
  float sw0 = e0 * inv, sw1 = e1 * inv;
  if (tid == 0) { sw_out[bl * 2] = sw0; sw_out[bl * 2 + 1] = sw1; }
  for (int h = tid; h < HID; h += 256) {
    float v = sw0 * H[(size_t)bl * HID + h] + sw1 * G[(size_t)bl * HID + h];
    Vbf[(size_t)bl * HID + h] = f2bf(v);
  }
}

// ---------------- E4: z_t/z_s -> alpha/beta -> c_hat+hiddens ----------------
__global__ __launch_bounds__(256) void k_attn(
    const float* __restrict__ PV, const float* __restrict__ PG,
    const float* __restrict__ SS, const float* __restrict__ wh,
    const unsigned short* __restrict__ stbf, const unsigned short* __restrict__ Vbf,
    const float* __restrict__ hiddens,
    float* __restrict__ alpha_out, float* __restrict__ beta_out,
    unsigned short* __restrict__ chh)
{
  const int TG = 4;
  int b  = blockIdx.x / (TT / TG);
  int t0 = (blockIdx.x % (TT / TG)) * TG;
  int tid = threadIdx.x;
  __shared__ float pg_s[TG][LL], wh_s[LL], zz[TG][LL + 1], alpha_s[TG][LL], beta_sh[TG];

  if (tid < LL) wh_s[tid] = wh[tid];
  if (tid < TG * LL) {
    int tt = tid / LL, k = tid - tt * LL;
    pg_s[tt][k] = PG[(size_t)(b * TT + t0 + tt) * 64 + k];
  }
  __syncthreads();

  if (tid < TG * (LL + 1)) {
    int tt = tid / (LL + 1), l = tid - tt * (LL + 1);
    const float* src = (l < LL) ? &PV[((size_t)b * LL + l) * 64]
                                : &SS[(size_t)(b * TT + t0 + tt) * 64];
    float acc = 0.f;
    for (int k = 0; k < LL; ++k) acc += fast_tanh(src[k] + pg_s[tt][k]) * wh_s[k];
    zz[tt][l] = acc;
  }
  __syncthreads();

  if (tid < TG) {
    int tt = tid, bt = b * TT + t0 + tt;
    float mx = -1e30f;
    for (int l = 0; l < LL; ++l) mx = fmaxf(mx, zz[tt][l]);
    float sum = 0.f;
    for (int l = 0; l < LL; ++l) { float e = __expf(zz[tt][l] - mx); alpha_s[tt][l] = e; sum += e; }
    float inv = 1.f / sum;
    for (int l = 0; l < LL; ++l) {
      alpha_s[tt][l] *= inv;
      alpha_out[(size_t)bt * LL + l] = alpha_s[tt][l];
    }
    float mx2 = fmaxf(mx, zz[tt][LL]);
    float s2 = 0.f;
    for (int l = 0; l <= LL; ++l) s2 += __expf(zz[tt][l] - mx2);
    float bet = __expf(zz[tt][LL] - mx2) / s2;
    beta_sh[tt] = bet;
    beta_out[bt] = bet;
  }
  __syncthreads();

  for (int h = tid; h < HID; h += 256) {
    float ct[TG] = {0.f, 0.f, 0.f, 0.f};
    for (int l = 0; l < LL; ++l) {
      float v = bf2f(Vbf[((size_t)b * LL + l) * HID + h]);
#pragma unroll
      for (int tt = 0; tt < TG; ++tt) ct[tt] += alpha_s[tt][l] * v;
    }
#pragma unroll
    for (int tt = 0; tt < TG; ++tt) {
      int bt = b * TT + t0 + tt;
      float bet = beta_sh[tt];
      float s = bf2f(stbf[(size_t)bt * HID + h]);
      float chat = bet * s + (1.f - bet) * ct[tt];
      chh[(size_t)bt * HID + h] = f2bf(chat + hiddens[(size_t)bt * HID + h]);
    }
  }
}

// ---------------- launcher ----------------
extern "C" void kernel_launch(void* const* d_in, const int* in_sizes, int n_in,
                              void* d_out, int out_size, void* d_ws, size_t ws_size,
                              hipStream_t stream)
{
  const float* x       = (const float*)d_in[0];
  const float* hiddens = (const float*)d_in[1];
  const float* cells   = (const float*)d_in[2];
  const float* G       = (const float*)d_in[3];
  const float* H       = (const float*)d_in[4];
  const float* W_sx    = (const float*)d_in[5];
  const float* W_sh    = (const float*)d_in[6];
  const float* W_ax    = (const float*)d_in[7];
  const float* W_ah    = (const float*)d_in[8];
  const float* W_ag    = (const float*)d_in[9];
  const float* w_sw    = (const float*)d_in[10];
  const float* Wv      = (const float*)d_in[11];
  const float* Wg      = (const float*)d_in[12];
  const float* Ws      = (const float*)d_in[13];
  const float* wh      = (const float*)d_in[14];
  const float* W_mlp   = (const float*)d_in[15];
  const float* b_mlp   = (const float*)d_in[16];

  float* scores = (float*)d_out;
  float* alpha  = scores + (size_t)BT * VOC;
  float* beta   = alpha + (size_t)BT * LL;
  float* swout  = beta + BT;

  char* wsp = (char*)d_ws;
  size_t off = 0;
  auto alloc = [&](size_t bytes) -> char* {
    char* p = wsp + off;
    off += (bytes + 255) & ~(size_t)255;
    return p;
  };

  unsigned short* xh     = (unsigned short*)alloc((size_t)BT * K2 * 2);   // [x | hprev]
  unsigned short* wsxh   = (unsigned short*)alloc((size_t)HID * K2 * 2);  // [W_sx | W_sh]
  unsigned short* waxb   = (unsigned short*)alloc((size_t)HID * E2 * 2);
  unsigned short* wahb   = (unsigned short*)alloc((size_t)HID * HID * 2);
  unsigned short* wagb   = (unsigned short*)alloc((size_t)HID * HID * 2);
  unsigned short* Hbf    = (unsigned short*)alloc((size_t)BL * HID * 2);
  unsigned short* Gbf    = (unsigned short*)alloc((size_t)BL * HID * 2);
  unsigned short* hidbf  = (unsigned short*)alloc((size_t)BT * HID * 2);
  unsigned short* wvb    = (unsigned short*)alloc((size_t)NPAD_S * HID * 2);
  unsigned short* wgb    = (unsigned short*)alloc((size_t)NPAD_S * HID * 2);
  unsigned short* wsb    = (unsigned short*)alloc((size_t)NPAD_S * HID * 2);
  unsigned short* wmlpb  = (unsigned short*)alloc((size_t)NPAD_MLP * HID * 2);
  unsigned short* Vbf    = (unsigned short*)alloc((size_t)BL * HID * 2);
  unsigned short* stbf   = (unsigned short*)alloc((size_t)BT * HID * 2);
  unsigned short* chh    = (unsigned short*)alloc((size_t)BT * HID * 2);
  unsigned short* xmbf   = (unsigned short*)alloc((size_t)BB * E2 * 2);
  unsigned short* AH     = (unsigned short*)alloc((size_t)BL * HID * 2);
  unsigned short* AG     = (unsigned short*)alloc((size_t)BL * HID * 2);
  float* qb = (float*)alloc((size_t)BB * HID * 4);
  float* PV = (float*)alloc((size_t)BL * 64 * 4);
  float* PG = (float*)alloc((size_t)BT * 64 * 4);
  float* SS = (float*)alloc((size_t)BT * 64 * 4);
  (void)ws_size; (void)in_sizes; (void)n_in; (void)out_size;

  // --- 1: fused converts (strided-dst) ---
  SegTable tab;
  int blk = 0, si = 0;
  auto seg = [&](const float* s, unsigned short* d, int n4, int rl4, int dstride4,
                 int dcol4, int nrows, int mode) {
    tab.s[si].src = s; tab.s[si].dst = d; tab.s[si].n4 = n4; tab.s[si].rl4 = rl4;
    tab.s[si].dstride4 = dstride4; tab.s[si].dcol4 = dcol4;
    tab.s[si].nrows = nrows; tab.s[si].mode = mode; tab.s[si].blk0 = blk;
    blk += (n4 + CHUNK4 - 1) / CHUNK4; ++si;
  };
  seg(W_sx,    wsxh,  HID * 384, 384, 576, 0,   0, 0);
  seg(W_sh,    wsxh,  HID * 192, 192, 576, 384, 0, 0);
  seg(x,       xh,    BT * 384,  384, 576, 0,   0, 0);
  seg(hiddens, xh,    BT * 192,  192, 576, 384, 0, 2);   // shifted h_{t-1}
  seg(W_ax,    waxb,  HID * 384, 384, 384, 0,   0, 0);
  seg(W_ah,    wahb,  HID * 192, 192, 192, 0,   0, 0);
  seg(W_ag,    wagb,  HID * 192, 192, 192, 0,   0, 0);
  seg(H,       Hbf,   BL * 192,  192, 192, 0,   0, 0);
  seg(G,       Gbf,   BL * 192,  192, 192, 0,   0, 0);
  seg(hiddens, hidbf, BT * 192,  192, 192, 0,   0, 0);
  seg(Wv,      wvb,   NPAD_S * 192, 192, 192, 0, LL, 1);
  seg(Wg,      wgb,   NPAD_S * 192, 192, 192, 0, LL, 1);
  seg(Ws,      wsb,   NPAD_S * 192, 192, 192, 0, LL, 1);
  seg(W_mlp,   wmlpb, NPAD_MLP * 192, 192, 192, 0, VOC, 1);
  k_convall<<<blk, 256, 0, stream>>>(tab);

  // --- 2: x time-mean (for q) ---
  k_xmean<<<BB * 6, 256, 0, stream>>>(x, xmbf);

  // --- 3: mega GEMM on 128x64 2-phase (972 blocks): st(fused), ah, ag, q ---
  SSegTable mt;
  mt.s[0] = SSeg{xh,   wsxh, nullptr, nullptr, cells, stbf, BT, HID, K2,  30, 0,   1};
  mt.s[1] = SSeg{Hbf,  wahb, nullptr, nullptr, nullptr, AH, BL, HID, HID, 25, 360, 2};
  mt.s[2] = SSeg{Gbf,  wagb, nullptr, nullptr, nullptr, AG, BL, HID, HID, 25, 660, 2};
  mt.s[3] = SSeg{xmbf, waxb, qb,      nullptr, nullptr, nullptr, BB, HID, E2,  1,  960, 0};
  gemm_bt64_seg<<<972, 256, 0, stream>>>(mt);

  // --- 4: switch ---
  k_switch<<<BL, 256, 0, stream>>>(AH, AG, qb, w_sw, H, G, Vbf, swout);

  // --- 5: skinny GEMMs ---
  SSegTable st;
  st.s[0] = SSeg{Vbf,   wvb, PV, nullptr, nullptr, nullptr, BL, 64, HID, 25, 0,  0};
  st.s[1] = SSeg{hidbf, wgb, PG, nullptr, nullptr, nullptr, BT, 64, HID, 30, 25, 0};
  st.s[2] = SSeg{stbf,  wsb, SS, nullptr, nullptr, nullptr, BT, 64, HID, 30, 55, 0};
  st.s[3] = st.s[2]; st.s[3].blk0 = 0x7fffffff;
  gemm_bt64_seg<<<85, 256, 0, stream>>>(st);

  // --- 6: attention epilogue ---
  k_attn<<<BB * (TT / 4), 256, 0, stream>>>(PV, PG, SS, wh, stbf, Vbf, hiddens,
                                            alpha, beta, chh);

  // --- 7: scores GEMM: 128x256 tile, 1200 blocks, 2 blk/CU ---
  gemm_sc2<<<30 * 40, 256, 73728, stream>>>(chh, wmlpb, scores, b_mlp, BT, VOC, HID, 30);
}

// Round 14
// 293.595 us; speedup vs baseline: 5.1642x; 1.0246x over previous
//
#include <hip/hip_runtime.h>

#define BB 64
#define TT 60
#define LL 49
#define HID 768
#define E2 1536
#define K2 2304          // E2 + HID (concat for s_t GEMM)
#define VOC 10000
#define BT (BB*TT)      // 3840
#define BL (BB*LL)      // 3136
#define NPAD_MLP 10240
#define NPAD_S 128

typedef __bf16 bf16x8 __attribute__((ext_vector_type(8)));
typedef float f32x4 __attribute__((ext_vector_type(4)));

__device__ __forceinline__ unsigned short f2bf(float f) {
  union { float f; unsigned int u; } v; v.f = f;
  unsigned int u = v.u;
  return (unsigned short)((u + 0x7fffu + ((u >> 16) & 1u)) >> 16);  // RNE
}
__device__ __forceinline__ float bf2f(unsigned short h) {
  union { unsigned int u; float f; } v; v.u = ((unsigned int)h) << 16;
  return v.f;
}
__device__ __forceinline__ float fast_tanh(float x) {
  float e = __expf(2.f * x);
  return 1.f - 2.f / (e + 1.f);
}
__device__ __forceinline__ float fast_sigmoid(float x) {
  return 1.f / (1.f + __expf(-x));
}

// ---------------- fused convert with strided destination ----------------
#define NSEG 14
#define CHUNK4 2048
struct SegT {
  const float* src;
  unsigned short* dst;
  int n4, rl4, dstride4, dcol4, nrows, mode, blk0;
};
struct SegTable { SegT s[NSEG]; };

__global__ __launch_bounds__(256) void k_convall(SegTable tab) {
  int b = blockIdx.x;
  int si = 0;
#pragma unroll
  for (int i = 1; i < NSEG; ++i) si += (b >= tab.s[i].blk0);
  SegT sg = tab.s[si];
  int lb = b - sg.blk0;
  int end = (lb + 1) * CHUNK4; end = end < sg.n4 ? end : sg.n4;
  for (int i = lb * CHUNK4 + threadIdx.x; i < end; i += 256) {
    int row = i / sg.rl4, c = i - row * sg.rl4;
    ushort4 o; o.x = o.y = o.z = o.w = 0;
    if (sg.mode == 0) {
      float4 v = ((const float4*)sg.src)[i];
      o.x = f2bf(v.x); o.y = f2bf(v.y); o.z = f2bf(v.z); o.w = f2bf(v.w);
    } else if (sg.mode == 1) {
      if (row < sg.nrows) {
        float4 v = ((const float4*)sg.src)[i];
        o.x = f2bf(v.x); o.y = f2bf(v.y); o.z = f2bf(v.z); o.w = f2bf(v.w);
      }
    } else {
      if (row % TT != 0) {
        float4 v = ((const float4*)sg.src)[i - sg.rl4];
        o.x = f2bf(v.x); o.y = f2bf(v.y); o.z = f2bf(v.z); o.w = f2bf(v.w);
      }
    }
    ((ushort4*)sg.dst)[(size_t)row * sg.dstride4 + sg.dcol4 + c] = o;
  }
}

// ---------------- k_xmean ----------------
__global__ __launch_bounds__(256) void k_xmean(const float* __restrict__ x,
                                               unsigned short* __restrict__ xm) {
  int b = blockIdx.x / 6;
  int c = (blockIdx.x % 6) * 256 + threadIdx.x;
  float s = 0.f;
  for (int t = 0; t < TT; ++t) s += x[((size_t)b * TT + t) * E2 + c];
  xm[(size_t)b * E2 + c] = f2bf(s * (1.f / 60.f));
}

// ---------------- segmented 128x64 2-phase GEMM (skinny only) ----------------
struct SSeg {
  const unsigned short* A; const unsigned short* B;
  float* C; const float* bias; const float* aux; unsigned short* outbf;
  int M, Nout, K, nMblk, blk0, emode;
};
#define NSSEG 4
struct SSegTable { SSeg s[NSSEG]; };

__global__ __launch_bounds__(256) void gemm_bt64_seg(SSegTable tab)
{
  __shared__ __attribute__((aligned(16))) unsigned short As[128*32];
  __shared__ __attribute__((aligned(16))) unsigned short Bs[64*32];
  const int tid  = threadIdx.x;
  const int lane = tid & 63;
  const int wave = tid >> 6;

  const int nwg = gridDim.x;
  const int id  = blockIdx.x;
  const int q = nwg >> 3, r = nwg & 7;
  const int xcd = id & 7, lo = id >> 3;
  const int wgid = (xcd < r ? xcd * (q + 1) : r * (q + 1) + (xcd - r) * q) + lo;

  int si = 0;
#pragma unroll
  for (int i = 1; i < NSSEG; ++i) si += (wgid >= tab.s[i].blk0);
  const SSeg sg = tab.s[si];
  const int lwg = wgid - sg.blk0;
  const int mb = lwg % sg.nMblk;
  const int nb = lwg / sg.nMblk;
  const int M = sg.M, Nout = sg.Nout, K = sg.K;
  const unsigned short* __restrict__ A  = sg.A;
  const unsigned short* __restrict__ Bw = sg.B;
  const int m0 = mb * 128;
  const int n0 = nb * 64;
  const int wm = (wave & 1) * 64;
  const int wn = (wave >> 1) * 32;

  f32x4 acc[4][2];
#pragma unroll
  for (int i = 0; i < 4; ++i)
#pragma unroll
    for (int j = 0; j < 2; ++j) acc[i][j] = f32x4{0.f, 0.f, 0.f, 0.f};

  const int lrow = lane & 15;
  const int kb   = (lane >> 4) * 8;

  for (int k0 = 0; k0 < K; k0 += 32) {
    __syncthreads();
#pragma unroll
    for (int p = 0; p < 2; ++p) {
      int slot = p * 256 + wave * 64 + lane;
      int row = slot >> 2, c8 = slot & 3;
      int ar = m0 + row; ar = ar < M ? ar : (M - 1);
      const unsigned short* asrc = A + (size_t)ar * K + k0 + c8 * 8;
      __builtin_amdgcn_global_load_lds(
          (const __attribute__((address_space(1))) void*)asrc,
          (__attribute__((address_space(3))) void*)&As[slot * 8],
          16, 0, 0);
    }
    {
      int slot = wave * 64 + lane;
      int row = slot >> 2, c8 = slot & 3;
      const unsigned short* bsrc = Bw + (size_t)(n0 + row) * K + k0 + c8 * 8;
      __builtin_amdgcn_global_load_lds(
          (const __attribute__((address_space(1))) void*)bsrc,
          (__attribute__((address_space(3))) void*)&Bs[slot * 8],
          16, 0, 0);
    }
    __syncthreads();

    bf16x8 av[4], bv[2];
#pragma unroll
    for (int i = 0; i < 4; ++i)
      av[i] = *(const bf16x8*)&As[(wm + i * 16 + lrow) * 32 + kb];
#pragma unroll
    for (int j = 0; j < 2; ++j)
      bv[j] = *(const bf16x8*)&Bs[(wn + j * 16 + lrow) * 32 + kb];
#pragma unroll
    for (int i = 0; i < 4; ++i)
#pragma unroll
      for (int j = 0; j < 2; ++j)
        acc[i][j] = __builtin_amdgcn_mfma_f32_16x16x32_bf16(av[i], bv[j], acc[i][j], 0, 0, 0);
  }

  const int cr = (lane >> 4) * 4;
  const int cc = lane & 15;
  float* __restrict__ C = sg.C;
#pragma unroll
  for (int i = 0; i < 4; ++i) {
    int row0 = m0 + wm + i * 16 + cr;
#pragma unroll
    for (int j = 0; j < 2; ++j) {
      int col = n0 + wn + j * 16 + cc;
      if (col < Nout) {
#pragma unroll
        for (int r2 = 0; r2 < 4; ++r2) {
          int row = row0 + r2;
          if (row < M) C[(size_t)row * Nout + col] = acc[i][j][r2];
        }
      }
    }
  }
}

// ---------------- 128^2 pipelined GEMM (mega): BK=32, 2-buffer, 32KB, 3 blk/CU ----------------
// R10's proven lean schedule scaled to 128^2 / 4 waves (wave-tile 64x64,
// acc[4][4]=64 regs). (256,3): cap ~170 VGPR (no spill), 3 blk/CU x 486 blocks
// -> cross-block overlap AND counted-vmcnt in-block pipelining.
// Tile kt uses buf c=kt&1; PH0(kt) stages B(kt+1)->buf c^1 (dead since barrier
// closing kt-1); PH1(kt) stages A(kt+2)->buf c (A reads done at PH0's barrier).
// VM2 at tile end: all but 2 newest (A(kt+2)) arrived => A(kt+1),B(kt+1) ready.
// Swizzle (both-sides, rule #21): 16B-slot s' = s ^ ((row>>1)&3).
// LDS buf: A 8KB @ +0, B 8KB @ +8192, stride 16384; total 32768.
#define BARR() do { asm volatile("" ::: "memory"); __builtin_amdgcn_s_barrier(); \
                    asm volatile("" ::: "memory"); } while (0)
#define VM2() asm volatile("s_waitcnt vmcnt(2)" ::: "memory")
#define VM0() asm volatile("s_waitcnt vmcnt(0)" ::: "memory")
#define VM6() asm volatile("s_waitcnt vmcnt(6)" ::: "memory")

struct GSeg {
  const unsigned short* A; const unsigned short* B;
  float* C; const float* bias; const float* aux; unsigned short* outbf;
  int M, Nout, K, nMblk, blk0, emode;
};
#define NGSEG 5
struct GSegTable { GSeg s[NGSEG]; };

#define P128_ST(bufi, op, kt) do {                                              \
  int k0_ = (kt) * 32;                                                          \
  _Pragma("unroll")                                                             \
  for (int l_ = 0; l_ < 2; ++l_) {                                              \
    int slot_ = l_ * 256 + tid;                                                 \
    int row_ = slot_ >> 2;                                                      \
    int ss_ = (slot_ & 3) ^ ((row_ >> 1) & 3);                                  \
    int gr_;                                                                    \
    if (op) gr_ = n0 + row_;                                                    \
    else { gr_ = m0 + row_; gr_ = gr_ < M ? gr_ : (M - 1); }                    \
    const unsigned short* src_ = ((op) ? Bw : Ap) + (size_t)gr_ * K + k0_ + ss_ * 8; \
    char* dst_ = smem + (bufi) * 16384 + (op) * 8192 + slot_ * 16;              \
    __builtin_amdgcn_global_load_lds(                                           \
        (const __attribute__((address_space(1))) void*)src_,                    \
        (__attribute__((address_space(3))) void*)dst_, 16, 0, 0);               \
  }                                                                             \
} while (0)

#define P128_LDA(bufi, row) (*(const bf16x8*)(smem + (bufi) * 16384 + (row) * 64 + ((cg ^ (((row) >> 1) & 3)) * 16)))
#define P128_LDB(bufi, row) (*(const bf16x8*)(smem + (bufi) * 16384 + 8192 + (row) * 64 + ((cg ^ (((row) >> 1) & 3)) * 16)))

#define P128_PH0(bufi, STAGE_STMT) do {                                         \
  STAGE_STMT;                                                                   \
  bf16x8 bfr0 = P128_LDB(bufi, wn + lrow);                                      \
  bf16x8 bfr1 = P128_LDB(bufi, wn + 16 + lrow);                                 \
  _Pragma("unroll")                                                             \
  for (int i_ = 0; i_ < 4; ++i_) afr[i_] = P128_LDA(bufi, wm + i_ * 16 + lrow); \
  __builtin_amdgcn_s_setprio(1);                                                \
  _Pragma("unroll")                                                             \
  for (int i_ = 0; i_ < 4; ++i_) {                                              \
    acc[i_][0] = __builtin_amdgcn_mfma_f32_16x16x32_bf16(afr[i_], bfr0, acc[i_][0], 0, 0, 0); \
    acc[i_][1] = __builtin_amdgcn_mfma_f32_16x16x32_bf16(afr[i_], bfr1, acc[i_][1], 0, 0, 0); \
  }                                                                             \
  __builtin_amdgcn_s_setprio(0);                                                \
  BARR();                                                                       \
} while (0)

#define P128_PH1(bufi, STAGE_STMT, VM_STMT) do {                                \
  STAGE_STMT;                                                                   \
  bf16x8 bfr0 = P128_LDB(bufi, wn + 32 + lrow);                                 \
  bf16x8 bfr1 = P128_LDB(bufi, wn + 48 + lrow);                                 \
  __builtin_amdgcn_s_setprio(1);                                                \
  _Pragma("unroll")                                                             \
  for (int i_ = 0; i_ < 4; ++i_) {                                              \
    acc[i_][2] = __builtin_amdgcn_mfma_f32_16x16x32_bf16(afr[i_], bfr0, acc[i_][2], 0, 0, 0); \
    acc[i_][3] = __builtin_amdgcn_mfma_f32_16x16x32_bf16(afr[i_], bfr1, acc[i_][3], 0, 0, 0); \
  }                                                                             \
  __builtin_amdgcn_s_setprio(0);                                                \
  VM_STMT;                                                                      \
  BARR();                                                                       \
} while (0)

__global__ __launch_bounds__(256, 3) void gemm_p128(GSegTable tab)
{
  extern __shared__ char smem[];
  const int tid  = threadIdx.x;
  const int lane = tid & 63;
  const int wave = tid >> 6;        // 0..3
  const int lrow = lane & 15;
  const int cg   = lane >> 4;

  const int nwg = gridDim.x;
  const int id  = blockIdx.x;
  const int q = nwg >> 3, r = nwg & 7;
  const int xcd = id & 7, lo = id >> 3;
  const int wgid = (xcd < r ? xcd * (q + 1) : r * (q + 1) + (xcd - r) * q) + lo;

  int si = 0;
#pragma unroll
  for (int i = 1; i < NGSEG; ++i) si += (wgid >= tab.s[i].blk0);
  const GSeg sg = tab.s[si];
  const int lwg = wgid - sg.blk0;
  const int mb = lwg % sg.nMblk;
  const int nb = lwg / sg.nMblk;
  const int M = sg.M, Nout = sg.Nout, K = sg.K;
  const unsigned short* __restrict__ Ap = sg.A;
  const unsigned short* __restrict__ Bw = sg.B;

  const int m0 = mb * 128;
  const int n0 = nb * 128;
  const int wm = (wave >> 1) * 64;
  const int wn = (wave & 1) * 64;

  f32x4 acc[4][4];
#pragma unroll
  for (int i = 0; i < 4; ++i)
#pragma unroll
    for (int j = 0; j < 4; ++j) acc[i][j] = f32x4{0.f, 0.f, 0.f, 0.f};
  bf16x8 afr[4];

  const int NT = K >> 5;  // >= 3

  // prologue: A(0),B(0),A(1) = 6 loads; VM2 -> A0,B0 arrived
  P128_ST(0, 0, 0);
  P128_ST(0, 1, 0);
  P128_ST(1, 0, 1);
  VM2();
  BARR();

  for (int kt = 0; kt < NT - 2; ++kt) {
    const int c = kt & 1;
    P128_PH0(c, P128_ST(c ^ 1, 1, kt + 1));
    P128_PH1(c, P128_ST(c, 0, kt + 2), VM2(););
  }
  {
    const int c = (NT - 2) & 1;
    P128_PH0(c, P128_ST(c ^ 1, 1, NT - 1));
    P128_PH1(c, ;, VM0(););
  }
  {
    const int c = (NT - 1) & 1;
    P128_PH0(c, ;);
    P128_PH1(c, ;, ;);
  }

  // epilogue: C/D layout col=lane&15, row=(lane>>4)*4+reg
  const int cr = (lane >> 4) * 4;
  const int cc = lane & 15;
  if (sg.emode == 0) {
    float* __restrict__ C = sg.C;
    const float* __restrict__ bias = sg.bias;
#pragma unroll
    for (int i = 0; i < 4; ++i) {
      int row0 = m0 + wm + i * 16 + cr;
#pragma unroll
      for (int j = 0; j < 4; ++j) {
        int col = n0 + wn + j * 16 + cc;
        if (col < Nout) {
          float badd = bias ? bias[col] : 0.f;
#pragma unroll
          for (int r2 = 0; r2 < 4; ++r2) {
            int row = row0 + r2;
            if (row < M) C[(size_t)row * Nout + col] = acc[i][j][r2] + badd;
          }
        }
      }
    }
  } else if (sg.emode == 1) {
    const float* __restrict__ cells = sg.aux;
    unsigned short* __restrict__ ob = sg.outbf;
#pragma unroll
    for (int i = 0; i < 4; ++i) {
      int row0 = m0 + wm + i * 16 + cr;
#pragma unroll
      for (int j = 0; j < 4; ++j) {
        int col = n0 + wn + j * 16 + cc;
        if (col < Nout) {
#pragma unroll
          for (int r2 = 0; r2 < 4; ++r2) {
            int row = row0 + r2;
            if (row < M) {
              float cv = cells[(size_t)row * Nout + col];
              ob[(size_t)row * Nout + col] = f2bf(fast_sigmoid(acc[i][j][r2]) * fast_tanh(cv));
            }
          }
        }
      }
    }
  } else {
    unsigned short* __restrict__ ob = sg.outbf;
#pragma unroll
    for (int i = 0; i < 4; ++i) {
      int row0 = m0 + wm + i * 16 + cr;
#pragma unroll
      for (int j = 0; j < 4; ++j) {
        int col = n0 + wn + j * 16 + cc;
        if (col < Nout) {
#pragma unroll
          for (int r2 = 0; r2 < 4; ++r2) {
            int row = row0 + r2;
            if (row < M) ob[(size_t)row * Nout + col] = f2bf(acc[i][j][r2]);
          }
        }
      }
    }
  }
}

// ---------------- scores GEMM: 128x256 tile, 4 waves, wave-tile 64x128 ----------------
// (unchanged from R13: 96us; short-K structural ceiling)
#define SC_STAGE(bufi, kt) do {                                                 \
  int k0_ = (kt) * 32;                                                          \
  _Pragma("unroll")                                                             \
  for (int l_ = 0; l_ < 2; ++l_) {                                              \
    int rr_ = l_ * 64 + wave * 16 + (lane >> 2);                                \
    int ss_ = (lane & 3) ^ ((rr_ >> 1) & 3);                                    \
    const unsigned short* src_ = Ap + (size_t)(m0 + rr_) * K + k0_ + ss_ * 8;   \
    char* dst_ = smem + (bufi) * 24576 + l_ * 4096 + wave * 1024;               \
    __builtin_amdgcn_global_load_lds(                                           \
        (const __attribute__((address_space(1))) void*)src_,                    \
        (__attribute__((address_space(3))) void*)dst_, 16, 0, 0);               \
  }                                                                             \
  _Pragma("unroll")                                                             \
  for (int l_ = 0; l_ < 4; ++l_) {                                              \
    int rr_ = l_ * 64 + wave * 16 + (lane >> 2);                                \
    int ss_ = (lane & 3) ^ ((rr_ >> 1) & 3);                                    \
    const unsigned short* src_ = Bw + (size_t)(n0 + rr_) * K + k0_ + ss_ * 8;   \
    char* dst_ = smem + (bufi) * 24576 + 8192 + l_ * 4096 + wave * 1024;        \
    __builtin_amdgcn_global_load_lds(                                           \
        (const __attribute__((address_space(1))) void*)src_,                    \
        (__attribute__((address_space(3))) void*)dst_, 16, 0, 0);               \
  }                                                                             \
} while (0)

#define SC_LDA(bufi, row) (*(const bf16x8*)(smem + (bufi) * 24576 + (row) * 64 + ((cg ^ (((row) >> 1) & 3)) * 16)))
#define SC_LDB(bufi, row) (*(const bf16x8*)(smem + (bufi) * 24576 + 8192 + (row) * 64 + ((cg ^ (((row) >> 1) & 3)) * 16)))

#define SC_TILE(bufi, STAGE_STMT, VM_STMT) do {                                 \
  STAGE_STMT;                                                                   \
  bf16x8 afr0 = SC_LDA(bufi, wm + lrow);                                        \
  bf16x8 afr1 = SC_LDA(bufi, wm + 16 + lrow);                                   \
  bf16x8 afr2 = SC_LDA(bufi, wm + 32 + lrow);                                   \
  bf16x8 afr3 = SC_LDA(bufi, wm + 48 + lrow);                                   \
  __builtin_amdgcn_s_setprio(1);                                                \
  _Pragma("unroll")                                                             \
  for (int j_ = 0; j_ < 8; ++j_) {                                              \
    bf16x8 b_ = SC_LDB(bufi, wn + j_ * 16 + lrow);                              \
    acc[0][j_] = __builtin_amdgcn_mfma_f32_16x16x32_bf16(afr0, b_, acc[0][j_], 0, 0, 0); \
    acc[1][j_] = __builtin_amdgcn_mfma_f32_16x16x32_bf16(afr1, b_, acc[1][j_], 0, 0, 0); \
    acc[2][j_] = __builtin_amdgcn_mfma_f32_16x16x32_bf16(afr2, b_, acc[2][j_], 0, 0, 0); \
    acc[3][j_] = __builtin_amdgcn_mfma_f32_16x16x32_bf16(afr3, b_, acc[3][j_], 0, 0, 0); \
  }                                                                             \
  __builtin_amdgcn_s_setprio(0);                                                \
  VM_STMT;                                                                      \
  BARR();                                                                       \
} while (0)

__global__ __launch_bounds__(256, 2) void gemm_sc2(
    const unsigned short* __restrict__ Ap,
    const unsigned short* __restrict__ Bw,
    float* __restrict__ C,
    const float* __restrict__ bias,
    int M, int Nout, int K, int nMblk)
{
  extern __shared__ char smem[];
  const int tid  = threadIdx.x;
  const int lane = tid & 63;
  const int wave = tid >> 6;
  const int lrow = lane & 15;
  const int cg   = lane >> 4;

  const int nwg = gridDim.x;
  const int id  = blockIdx.x;
  const int q = nwg >> 3, r = nwg & 7;
  const int xcd = id & 7, lo = id >> 3;
  const int wgid = (xcd < r ? xcd * (q + 1) : r * (q + 1) + (xcd - r) * q) + lo;
  const int mb = wgid % nMblk;
  const int nb = wgid / nMblk;

  const int m0 = mb * 128;
  const int n0 = nb * 256;
  const int wm = (wave >> 1) * 64;
  const int wn = (wave & 1) * 128;

  f32x4 acc[4][8];
#pragma unroll
  for (int i = 0; i < 4; ++i)
#pragma unroll
    for (int j = 0; j < 8; ++j) acc[i][j] = f32x4{0.f, 0.f, 0.f, 0.f};

  const int NT = K >> 5;  // 24

  SC_STAGE(0, 0);
  SC_STAGE(1, 1);
  VM6();
  BARR();

  int b = 0;
  for (int kt = 0; kt < NT - 2; ++kt) {
    int b2 = b + 2; if (b2 >= 3) b2 -= 3;
    SC_TILE(b, SC_STAGE(b2, kt + 2), VM6(););
    ++b; if (b == 3) b = 0;
  }
  SC_TILE(b, ;, VM0(););
  ++b; if (b == 3) b = 0;
  SC_TILE(b, ;, ;);

#pragma unroll
  for (int i = 0; i < 4; ++i) {
    int row0 = m0 + wm + i * 16 + (lane >> 4) * 4;
#pragma unroll
    for (int j = 0; j < 8; ++j) {
      int col = n0 + wn + j * 16 + (lane & 15);
      if (col < Nout) {
        float badd = bias ? bias[col] : 0.f;
#pragma unroll
        for (int r2 = 0; r2 < 4; ++r2)
          C[(size_t)(row0 + r2) * Nout + col] = acc[i][j][r2] + badd;
      }
    }
  }
}

// ---------------- E3: switch softmax + V (AH/AG bf16) ----------------
__global__ __launch_bounds__(256) void k_switch(
    const unsigned short* __restrict__ AH, const unsigned short* __restrict__ AG,
    const float* __restrict__ q, const float* __restrict__ wsw,
    const float* __restrict__ H, const float* __restrict__ G,
    unsigned short* __restrict__ Vbf, float* __restrict__ sw_out)
{
  int bl = blockIdx.x;
  int b = bl / LL;
  int tid = threadIdx.x;
  float aH = 0.f, aG = 0.f;
  for (int h = tid; h < HID; h += 256) {
    float qv = q[b * HID + h], w = wsw[h];
    aH += fast_tanh(bf2f(AH[(size_t)bl * HID + h]) + qv) * w;
    aG += fast_tanh(bf2f(AG[(size_t)bl * HID + h]) + qv) * w;
  }
#pragma unroll
  for (int off = 32; off > 0; off >>= 1) {
    aH += __shfl_down(aH, off);
    aG += __shfl_down(aG, off);
  }
  __shared__ float redH[4], redG[4];
  int lane = tid & 63, wave = tid >> 6;
  if (lane == 0) { redH[wave] = aH; redG[wave] = aG; }
  __syncthreads();
  float sH = redH[0] + redH[1] + redH[2] + redH[3];
  float sG = redG[0] + redG[1] + redG[2] + redG[3];
  float m = fmaxf(sH, sG);
  float e0 = __expf(sH - m), e1 = __expf(sG - m);
  float inv = 1.f / (e0 + e1);
  float sw0 = e0 * inv, sw1 = e1 * inv;
  if (tid == 0) { sw_out[bl * 2] = sw0; sw_out[bl * 2 + 1] = sw1; }
  for (int h = tid; h < HID; h += 256) {
    float v = sw0 * H[(size_t)bl * HID + h] + sw1 * G[(size_t)bl * HID + h];
    Vbf[(size_t)bl * HID + h] = f2bf(v);
  }
}

// ---------------- E4: attention epilogue ----------------
__global__ __launch_bounds__(256) void k_attn(
    const float* __restrict__ PV, const float* __restrict__ PG,
    const float* __restrict__ SS, const float* __restrict__ wh,
    const unsigned short* __restrict__ stbf, const unsigned short* __restrict__ Vbf,
    const float* __restrict__ hiddens,
    float* __restrict__ alpha_out, float* __restrict__ beta_out,
    unsigned short* __restrict__ chh)
{
  const int TG = 4;
  int b  = blockIdx.x / (TT / TG);
  int t0 = (blockIdx.x % (TT / TG)) * TG;
  int tid = threadIdx.x;
  __shared__ float pg_s[TG][LL], wh_s[LL], zz[TG][LL + 1], alpha_s[TG][LL], beta_sh[TG];

  if (tid < LL) wh_s[tid] = wh[tid];
  if (tid < TG * LL) {
    int tt = tid / LL, k = tid - tt * LL;
    pg_s[tt][k] = PG[(size_t)(b * TT + t0 + tt) * 64 + k];
  }
  __syncthreads();

  if (tid < TG * (LL + 1)) {
    int tt = tid / (LL + 1), l = tid - tt * (LL + 1);
    const float* src = (l < LL) ? &PV[((size_t)b * LL + l) * 64]
                                : &SS[(size_t)(b * TT + t0 + tt) * 64];
    float acc = 0.f;
    for (int k = 0; k < LL; ++k) acc += fast_tanh(src[k] + pg_s[tt][k]) * wh_s[k];
    zz[tt][l] = acc;
  }
  __syncthreads();

  if (tid < TG) {
    int tt = tid, bt = b * TT + t0 + tt;
    float mx = -1e30f;
    for (int l = 0; l < LL; ++l) mx = fmaxf(mx, zz[tt][l]);
    float sum = 0.f;
    for (int l = 0; l < LL; ++l) { float e = __expf(zz[tt][l] - mx); alpha_s[tt][l] = e; sum += e; }
    float inv = 1.f / sum;
    for (int l = 0; l < LL; ++l) {
      alpha_s[tt][l] *= inv;
      alpha_out[(size_t)bt * LL + l] = alpha_s[tt][l];
    }
    float mx2 = fmaxf(mx, zz[tt][LL]);
    float s2 = 0.f;
    for (int l = 0; l <= LL; ++l) s2 += __expf(zz[tt][l] - mx2);
    float bet = __expf(zz[tt][LL] - mx2) / s2;
    beta_sh[tt] = bet;
    beta_out[bt] = bet;
  }
  __syncthreads();

  for (int h = tid; h < HID; h += 256) {
    float ct[TG] = {0.f, 0.f, 0.f, 0.f};
    for (int l = 0; l < LL; ++l) {
      float v = bf2f(Vbf[((size_t)b * LL + l) * HID + h]);
#pragma unroll
      for (int tt = 0; tt < TG; ++tt) ct[tt] += alpha_s[tt][l] * v;
    }
#pragma unroll
    for (int tt = 0; tt < TG; ++tt) {
      int bt = b * TT + t0 + tt;
      float bet = beta_sh[tt];
      float s = bf2f(stbf[(size_t)bt * HID + h]);
      float chat = bet * s + (1.f - bet) * ct[tt];
      chh[(size_t)bt * HID + h] = f2bf(chat + hiddens[(size_t)bt * HID + h]);
    }
  }
}

// ---------------- launcher ----------------
extern "C" void kernel_launch(void* const* d_in, const int* in_sizes, int n_in,
                              void* d_out, int out_size, void* d_ws, size_t ws_size,
                              hipStream_t stream)
{
  const float* x       = (const float*)d_in[0];
  const float* hiddens = (const float*)d_in[1];
  const float* cells   = (const float*)d_in[2];
  const float* G       = (const float*)d_in[3];
  const float* H       = (const float*)d_in[4];
  const float* W_sx    = (const float*)d_in[5];
  const float* W_sh    = (const float*)d_in[6];
  const float* W_ax    = (const float*)d_in[7];
  const float* W_ah    = (const float*)d_in[8];
  const float* W_ag    = (const float*)d_in[9];
  const float* w_sw    = (const float*)d_in[10];
  const float* Wv      = (const float*)d_in[11];
  const float* Wg      = (const float*)d_in[12];
  const float* Ws      = (const float*)d_in[13];
  const float* wh      = (const float*)d_in[14];
  const float* W_mlp   = (const float*)d_in[15];
  const float* b_mlp   = (const float*)d_in[16];

  float* scores = (float*)d_out;
  float* alpha  = scores + (size_t)BT * VOC;
  float* beta   = alpha + (size_t)BT * LL;
  float* swout  = beta + BT;

  char* wsp = (char*)d_ws;
  size_t off = 0;
  auto alloc = [&](size_t bytes) -> char* {
    char* p = wsp + off;
    off += (bytes + 255) & ~(size_t)255;
    return p;
  };

  unsigned short* xh     = (unsigned short*)alloc((size_t)BT * K2 * 2);
  unsigned short* wsxh   = (unsigned short*)alloc((size_t)HID * K2 * 2);
  unsigned short* waxb   = (unsigned short*)alloc((size_t)HID * E2 * 2);
  unsigned short* wahb   = (unsigned short*)alloc((size_t)HID * HID * 2);
  unsigned short* wagb   = (unsigned short*)alloc((size_t)HID * HID * 2);
  unsigned short* Hbf    = (unsigned short*)alloc((size_t)BL * HID * 2);
  unsigned short* Gbf    = (unsigned short*)alloc((size_t)BL * HID * 2);
  unsigned short* hidbf  = (unsigned short*)alloc((size_t)BT * HID * 2);
  unsigned short* wvb    = (unsigned short*)alloc((size_t)NPAD_S * HID * 2);
  unsigned short* wgb    = (unsigned short*)alloc((size_t)NPAD_S * HID * 2);
  unsigned short* wsb    = (unsigned short*)alloc((size_t)NPAD_S * HID * 2);
  unsigned short* wmlpb  = (unsigned short*)alloc((size_t)NPAD_MLP * HID * 2);
  unsigned short* Vbf    = (unsigned short*)alloc((size_t)BL * HID * 2);
  unsigned short* stbf   = (unsigned short*)alloc((size_t)BT * HID * 2);
  unsigned short* chh    = (unsigned short*)alloc((size_t)BT * HID * 2);
  unsigned short* xmbf   = (unsigned short*)alloc((size_t)BB * E2 * 2);
  unsigned short* AH     = (unsigned short*)alloc((size_t)BL * HID * 2);
  unsigned short* AG     = (unsigned short*)alloc((size_t)BL * HID * 2);
  float* qb = (float*)alloc((size_t)BB * HID * 4);
  float* PV = (float*)alloc((size_t)BL * 64 * 4);
  float* PG = (float*)alloc((size_t)BT * 64 * 4);
  float* SS = (float*)alloc((size_t)BT * 64 * 4);
  (void)ws_size; (void)in_sizes; (void)n_in; (void)out_size;

  // --- 1: fused converts ---
  SegTable tab;
  int blk = 0, si = 0;
  auto seg = [&](const float* s, unsigned short* d, int n4, int rl4, int dstride4,
                 int dcol4, int nrows, int mode) {
    tab.s[si].src = s; tab.s[si].dst = d; tab.s[si].n4 = n4; tab.s[si].rl4 = rl4;
    tab.s[si].dstride4 = dstride4; tab.s[si].dcol4 = dcol4;
    tab.s[si].nrows = nrows; tab.s[si].mode = mode; tab.s[si].blk0 = blk;
    blk += (n4 + CHUNK4 - 1) / CHUNK4; ++si;
  };
  seg(W_sx,    wsxh,  HID * 384, 384, 576, 0,   0, 0);
  seg(W_sh,    wsxh,  HID * 192, 192, 576, 384, 0, 0);
  seg(x,       xh,    BT * 384,  384, 576, 0,   0, 0);
  seg(hiddens, xh,    BT * 192,  192, 576, 384, 0, 2);
  seg(W_ax,    waxb,  HID * 384, 384, 384, 0,   0, 0);
  seg(W_ah,    wahb,  HID * 192, 192, 192, 0,   0, 0);
  seg(W_ag,    wagb,  HID * 192, 192, 192, 0,   0, 0);
  seg(H,       Hbf,   BL * 192,  192, 192, 0,   0, 0);
  seg(G,       Gbf,   BL * 192,  192, 192, 0,   0, 0);
  seg(hiddens, hidbf, BT * 192,  192, 192, 0,   0, 0);
  seg(Wv,      wvb,   NPAD_S * 192, 192, 192, 0, LL, 1);
  seg(Wg,      wgb,   NPAD_S * 192, 192, 192, 0, LL, 1);
  seg(Ws,      wsb,   NPAD_S * 192, 192, 192, 0, LL, 1);
  seg(W_mlp,   wmlpb, NPAD_MLP * 192, 192, 192, 0, VOC, 1);
  k_convall<<<blk, 256, 0, stream>>>(tab);

  // --- 2: x time-mean ---
  k_xmean<<<BB * 6, 256, 0, stream>>>(x, xmbf);

  // --- 3: mega GEMM on pipelined 128^2 (486 blocks, 3 blk/CU) ---
  GSegTable mt;
  mt.s[0] = GSeg{xh,   wsxh, nullptr, nullptr, cells,   stbf,    BT, HID, K2,  30, 0,   1};
  mt.s[1] = GSeg{Hbf,  wahb, nullptr, nullptr, nullptr, AH,      BL, HID, HID, 25, 180, 2};
  mt.s[2] = GSeg{Gbf,  wagb, nullptr, nullptr, nullptr, AG,      BL, HID, HID, 25, 330, 2};
  mt.s[3] = GSeg{xmbf, waxb, qb,      nullptr, nullptr, nullptr, BB, HID, E2,  1,  480, 0};
  mt.s[4] = mt.s[3]; mt.s[4].blk0 = 0x7fffffff;
  gemm_p128<<<486, 256, 32768, stream>>>(mt);

  // --- 4: switch ---
  k_switch<<<BL, 256, 0, stream>>>(AH, AG, qb, w_sw, H, G, Vbf, swout);

  // --- 5: skinny GEMMs ---
  SSegTable st;
  st.s[0] = SSeg{Vbf,   wvb, PV, nullptr, nullptr, nullptr, BL, 64, HID, 25, 0,  0};
  st.s[1] = SSeg{hidbf, wgb, PG, nullptr, nullptr, nullptr, BT, 64, HID, 30, 25, 0};
  st.s[2] = SSeg{stbf,  wsb, SS, nullptr, nullptr, nullptr, BT, 64, HID, 30, 55, 0};
  st.s[3] = st.s[2]; st.s[3].blk0 = 0x7fffffff;
  gemm_bt64_seg<<<85, 256, 0, stream>>>(st);

  // --- 6: attention epilogue ---
  k_attn<<<BB * (TT / 4), 256, 0, stream>>>(PV, PG, SS, wh, stbf, Vbf, hiddens,
                                            alpha, beta, chh);

  // --- 7: scores GEMM ---
  gemm_sc2<<<30 * 40, 256, 73728, stream>>>(chh, wmlpb, scores, b_mlp, BT, VOC, HID, 30);
}